// Round 1
// baseline (695.245 us; speedup 1.0000x reference)
//
#include <hip/hip_runtime.h>
#include <hip/hip_bf16.h>

// Problem constants
constexpr int NPAT = 8192;     // B*PH*PW = 8*32*32
constexpr int PPP  = 16;       // PS*PS
constexpr int CCH  = 64;       // channels
constexpr int HIDc = 256;

// ---------------------------------------------------------------------------
// K1: unfold x [8,64,128,128] -> proc [8192,16,64]
__global__ __launch_bounds__(256) void k_extract(const float* __restrict__ x,
                                                 float* __restrict__ proc) {
    int idx = blockIdx.x * 256 + threadIdx.x;   // over 8192*16*64 = 8388608
    int c = idx & 63;
    int p = (idx >> 6) & 15;
    int n = idx >> 10;
    int b = n >> 10;
    int rem = n & 1023;
    int gy = rem >> 5, gx = rem & 31;
    int hh = gy * 4 + (p >> 2), ww = gx * 4 + (p & 3);
    proc[idx] = x[((b * 64 + c) * 128 + hh) * 128 + ww];
}

// ---------------------------------------------------------------------------
// K2: summary[n, c] = mean_p(pixel_positions) + MLP(coords)
__global__ __launch_bounds__(64) void k_summary(const float* __restrict__ pixpos,
                                                const float* __restrict__ w1,
                                                const float* __restrict__ b1,
                                                const float* __restrict__ w2,
                                                const float* __restrict__ b2,
                                                float* __restrict__ summary) {
    __shared__ float h[256];
    int n = blockIdx.x, t = threadIdx.x;  // 64 threads
    int rem = n & 1023;
    float cy = (float)(rem >> 5) * (1.f / 31.f);
    float cx = (float)(rem & 31) * (1.f / 31.f);
    for (int k = t; k < 256; k += 64) {
        float v = cy * w1[k] + cx * w1[256 + k] + b1[k];
        h[k] = v / (1.f + __expf(-v));   // silu
    }
    __syncthreads();
    float acc = b2[t];
    for (int k = 0; k < 256; ++k) acc += h[k] * w2[k * 64 + t];
    float pm = 0.f;
    for (int p = 0; p < 16; ++p) pm += pixpos[p * 64 + t];
    summary[n * 64 + t] = acc + pm * (1.f / 16.f);
}

// ---------------------------------------------------------------------------
// K3: per hyper-block: h1[n,256] = silu(summary @ wn_w1 + wn_b1)
//                      bias[n,64] = silu(summary @ bn_w1 + bn_b1) @ bn_w2 + bn_b2
// 4 patches per workgroup.
__global__ __launch_bounds__(256) void k_mlp(const float* __restrict__ summary,
                                             const float* __restrict__ w1w,
                                             const float* __restrict__ b1w,
                                             const float* __restrict__ w1b,
                                             const float* __restrict__ b1b,
                                             const float* __restrict__ w2b,
                                             const float* __restrict__ b2b,
                                             float* __restrict__ h1out,
                                             float* __restrict__ biasout) {
    __shared__ float ss[4][64];
    __shared__ float hb[4][257];
    int t = threadIdx.x;
    int n0 = blockIdx.x * 4;
    ss[t >> 6][t & 63] = summary[n0 * 64 + t];
    __syncthreads();
    float aw[4], ab[4];
    for (int g = 0; g < 4; ++g) { aw[g] = b1w[t]; ab[g] = b1b[t]; }
    for (int c = 0; c < 64; ++c) {
        float ww_ = w1w[c * 256 + t];
        float wb_ = w1b[c * 256 + t];
        for (int g = 0; g < 4; ++g) {
            aw[g] += ss[g][c] * ww_;
            ab[g] += ss[g][c] * wb_;
        }
    }
    for (int g = 0; g < 4; ++g) {
        float v = aw[g]; v = v / (1.f + __expf(-v));
        h1out[(n0 + g) * 256 + t] = v;
        float u = ab[g]; u = u / (1.f + __expf(-u));
        hb[g][t] = u;
    }
    __syncthreads();
    {
        int g = t >> 6, c = t & 63;
        float acc = b2b[c];
        for (int k = 0; k < 256; ++k) acc += hb[g][k] * w2b[k * 64 + c];
        biasout[(n0 + g) * 64 + c] = acc;
    }
}

// ---------------------------------------------------------------------------
// K4: wgt[n, m] = h1[n,:] @ w2[:, m] + b2[m], store bf16.  M=8192 N=4096 K=256
// fp32 tiled GEMM: 128x128 tile, TK=32, 256 threads, 8x8 micro-tile.
__global__ __launch_bounds__(256) void k_wgt_gemm(const float* __restrict__ h1,
                                                  const float* __restrict__ w2,
                                                  const float* __restrict__ b2,
                                                  __hip_bfloat16* __restrict__ wgt) {
    __shared__ float As[32][132];   // [k][n]  (transposed)
    __shared__ float Bs[32][132];   // [k][m]
    int t = threadIdx.x;
    int n0 = (blockIdx.x & 63) * 128;
    int m0 = (blockIdx.x >> 6) * 128;
    int tr = (t >> 4) * 8;   // n offset within tile
    int tc = (t & 15) * 8;   // m offset within tile
    float acc[8][8] = {};
    for (int k0 = 0; k0 < 256; k0 += 32) {
        // load A tile (transpose): h1[n0+r][k0+c]
        for (int it = 0; it < 4; ++it) {
            int fid = t + it * 256;           // 0..1023
            int r = fid >> 3;                 // 0..127
            int c4 = (fid & 7) * 4;           // 0..28
            float4 v = *(const float4*)&h1[(n0 + r) * 256 + k0 + c4];
            As[c4 + 0][r] = v.x; As[c4 + 1][r] = v.y;
            As[c4 + 2][r] = v.z; As[c4 + 3][r] = v.w;
        }
        // load B tile: w2[(k0+kr)*4096 + m0+mc]
        for (int it = 0; it < 4; ++it) {
            int fid = t + it * 256;
            int kr = fid >> 5;                // 0..31
            int mc4 = (fid & 31) * 4;         // 0..124
            *(float4*)&Bs[kr][mc4] = *(const float4*)&w2[(size_t)(k0 + kr) * 4096 + m0 + mc4];
        }
        __syncthreads();
        for (int k = 0; k < 32; ++k) {
            float a[8], b[8];
            *(float4*)(a)     = *(float4*)&As[k][tr];
            *(float4*)(a + 4) = *(float4*)&As[k][tr + 4];
            *(float4*)(b)     = *(float4*)&Bs[k][tc];
            *(float4*)(b + 4) = *(float4*)&Bs[k][tc + 4];
            for (int i = 0; i < 8; ++i)
                for (int j = 0; j < 8; ++j)
                    acc[i][j] += a[i] * b[j];
        }
        __syncthreads();
    }
    for (int i = 0; i < 8; ++i) {
        union { __hip_bfloat16 hh[8]; uint4 u; } st;
        for (int j = 0; j < 8; ++j)
            st.hh[j] = __float2bfloat16(acc[i][j] + b2[m0 + tc + j]);
        *(uint4*)&wgt[(size_t)(n0 + tr + i) * 4096 + m0 + tc] = st.u;
    }
}

// ---------------------------------------------------------------------------
// K5: per patch: normed = LN(proc); proc = normed @ wgt^T + bias + proc  (in place)
__global__ __launch_bounds__(256) void k_bmm(float* __restrict__ proc,
                                             const __hip_bfloat16* __restrict__ wgt,
                                             const float* __restrict__ bias,
                                             const float* __restrict__ ln_g,
                                             const float* __restrict__ ln_b) {
    __shared__ float pr[16][64];
    __shared__ float nm[16][65];
    __shared__ float wg[64][65];
    __shared__ float bs[64];
    int n = blockIdx.x, t = threadIdx.x;
    for (int it = 0; it < 4; ++it) {
        int idx = t + it * 256;
        pr[idx >> 6][idx & 63] = proc[n * 1024 + idx];
    }
    if (t < 64) bs[t] = bias[n * 64 + t];
    // wgt row (4096 bf16) -> LDS floats
    for (int q = 0; q < 2; ++q) {
        int base = t * 16 + q * 8;
        union { uint4 u; unsigned short s[8]; } cv;
        cv.u = *(const uint4*)&wgt[(size_t)n * 4096 + base];
        int i = base >> 6, j = base & 63;
        for (int e = 0; e < 8; ++e) {
            unsigned int ub = ((unsigned int)cv.s[e]) << 16;
            wg[i][j + e] = __uint_as_float(ub);
        }
    }
    __syncthreads();
    // LayerNorm over channels (64) per token p
    {
        int p = t >> 4, l = t & 15;
        float s = 0.f, s2 = 0.f;
        for (int c = l; c < 64; c += 16) { float v = pr[p][c]; s += v; s2 += v * v; }
        for (int m = 1; m < 16; m <<= 1) { s += __shfl_xor(s, m); s2 += __shfl_xor(s2, m); }
        float mean = s * (1.f / 64.f);
        float var = s2 * (1.f / 64.f) - mean * mean;
        float rinv = rsqrtf(var + 1e-5f);
        for (int c = l; c < 64; c += 16)
            nm[p][c] = (pr[p][c] - mean) * rinv * ln_g[c] + ln_b[c];
    }
    __syncthreads();
    // out[p][i] = sum_j wg[i][j]*nm[p][j] + bs[i] + pr[p][i]
    {
        int p = t >> 4, il = t & 15;
        float o[4] = {0.f, 0.f, 0.f, 0.f};
        for (int j = 0; j < 64; ++j) {
            float nv = nm[p][j];
            o[0] += nv * wg[il][j];
            o[1] += nv * wg[il + 16][j];
            o[2] += nv * wg[il + 32][j];
            o[3] += nv * wg[il + 48][j];
        }
        for (int r = 0; r < 4; ++r) {
            int i = il + r * 16;
            proc[n * 1024 + p * 64 + i] = o[r] + bs[i] + pr[p][i];
        }
    }
}

// ---------------------------------------------------------------------------
// K6: 1x1 conv (64->256) + pixel shuffle r=2 -> out [8,64,256,256]
__global__ __launch_bounds__(256) void k_conv(const float* __restrict__ proc,
                                              const float* __restrict__ cw,
                                              const float* __restrict__ cb,
                                              float* __restrict__ out) {
    __shared__ float ms[64][132];   // merged[cc][w] for one (b,h) row
    int bid = blockIdx.x, t = threadIdx.x;
    int b = bid >> 7, h = bid & 127;
    int gy = h >> 2, py = h & 3;
    for (int it = 0; it < 32; ++it) {
        int idx = t + it * 256;          // w*64 + cc
        int w = idx >> 6, cc = idx & 63;
        int n = (b << 10) + (gy << 5) + (w >> 2);
        int p = (py << 2) + (w & 3);
        ms[cc][w] = proc[(n << 10) + (p << 6) + cc];
    }
    __syncthreads();
    int oc0 = (t & 31) * 8;
    for (int half = 0; half < 2; ++half) {
        int w0 = (t >> 5) * 8 + half * 64;
        float acc[8][8] = {};            // [w][oc]
        for (int cc = 0; cc < 64; ++cc) {
            float a[8], m8[8];
            *(float4*)(a)      = *(const float4*)&cw[cc * 256 + oc0];
            *(float4*)(a + 4)  = *(const float4*)&cw[cc * 256 + oc0 + 4];
            *(float4*)(m8)     = *(float4*)&ms[cc][w0];
            *(float4*)(m8 + 4) = *(float4*)&ms[cc][w0 + 4];
            for (int i = 0; i < 8; ++i)
                for (int j = 0; j < 8; ++j)
                    acc[i][j] += m8[i] * a[j];
        }
        for (int j = 0; j < 8; j += 2) {
            int oc = oc0 + j;
            int c = oc >> 2, s1 = (oc >> 1) & 1;
            float2* orow = (float2*)&out[(((size_t)b * 64 + c) * 256 + 2 * h + s1) * 256];
            float b0 = cb[oc], b1 = cb[oc + 1];
            for (int i = 0; i < 8; ++i)
                orow[w0 + i] = make_float2(acc[i][j] + b0, acc[i][j + 1] + b1);
        }
    }
}

// ---------------------------------------------------------------------------
extern "C" void kernel_launch(void* const* d_in, const int* in_sizes, int n_in,
                              void* d_out, int out_size, void* d_ws, size_t ws_size,
                              hipStream_t stream) {
    const float* x      = (const float*)d_in[0];
    const float* pixpos = (const float*)d_in[1];
    const float* ppe_w1 = (const float*)d_in[2];
    const float* ppe_b1 = (const float*)d_in[3];
    const float* ppe_w2 = (const float*)d_in[4];
    const float* ppe_b2 = (const float*)d_in[5];
    const float* ln_g   = (const float*)d_in[6];
    const float* ln_b   = (const float*)d_in[7];
    const float* wn_w1  = (const float*)d_in[8];
    const float* wn_b1  = (const float*)d_in[9];
    const float* wn_w2  = (const float*)d_in[10];
    const float* wn_b2  = (const float*)d_in[11];
    const float* bn_w1  = (const float*)d_in[12];
    const float* bn_b1  = (const float*)d_in[13];
    const float* bn_w2  = (const float*)d_in[14];
    const float* bn_b2  = (const float*)d_in[15];
    const float* conv_w = (const float*)d_in[16];
    const float* conv_b = (const float*)d_in[17];
    float* out = (float*)d_out;

    char* wsb = (char*)d_ws;
    float* proc    = (float*)wsb;  wsb += (size_t)NPAT * 1024 * 4;   // 32 MB
    float* summary = (float*)wsb;  wsb += (size_t)NPAT * 64 * 4;     //  2 MB
    float* h1      = (float*)wsb;  wsb += (size_t)NPAT * 256 * 4;    //  8 MB
    float* bias    = (float*)wsb;  wsb += (size_t)NPAT * 64 * 4;     //  2 MB
    __hip_bfloat16* wgt = (__hip_bfloat16*)wsb;                      // 64 MB

    k_extract<<<32768, 256, 0, stream>>>(x, proc);
    k_summary<<<NPAT, 64, 0, stream>>>(pixpos, ppe_w1, ppe_b1, ppe_w2, ppe_b2, summary);
    for (int i = 0; i < 2; ++i) {
        k_mlp<<<NPAT / 4, 256, 0, stream>>>(summary,
                                            wn_w1 + (size_t)i * 64 * 256, wn_b1 + i * 256,
                                            bn_w1 + (size_t)i * 64 * 256, bn_b1 + i * 256,
                                            bn_w2 + (size_t)i * 256 * 64, bn_b2 + i * 64,
                                            h1, bias);
        k_wgt_gemm<<<2048, 256, 0, stream>>>(h1, wn_w2 + (size_t)i * 256 * 4096,
                                             wn_b2 + (size_t)i * 4096, wgt);
        k_bmm<<<NPAT, 256, 0, stream>>>(proc, wgt, bias, ln_g + i * 64, ln_b + i * 64);
    }
    k_conv<<<1024, 256, 0, stream>>>(proc, conv_w, conv_b, out);
}

// Round 2
// 389.382 us; speedup vs baseline: 1.7855x; 1.7855x over previous
//
#include <hip/hip_runtime.h>
#include <hip/hip_bf16.h>

// Problem constants
constexpr int NPAT = 8192;     // B*PH*PW = 8*32*32

typedef __attribute__((ext_vector_type(8))) short short8v;   // 8 bf16
typedef __attribute__((ext_vector_type(4))) float f32x4;

#define GLOAD16(g, l) __builtin_amdgcn_global_load_lds( \
    (const __attribute__((address_space(1))) void*)(g), \
    (__attribute__((address_space(3))) void*)(l), 16, 0, 0)

// ---------------------------------------------------------------------------
// K1: unfold x [8,64,128,128] -> proc [8192,16,64]
__global__ __launch_bounds__(256) void k_extract(const float* __restrict__ x,
                                                 float* __restrict__ proc) {
    int idx = blockIdx.x * 256 + threadIdx.x;   // over 8192*16*64 = 8388608
    int c = idx & 63;
    int p = (idx >> 6) & 15;
    int n = idx >> 10;
    int b = n >> 10;
    int rem = n & 1023;
    int gy = rem >> 5, gx = rem & 31;
    int hh = gy * 4 + (p >> 2), ww = gx * 4 + (p & 3);
    proc[idx] = x[((b * 64 + c) * 128 + hh) * 128 + ww];
}

// ---------------------------------------------------------------------------
// K2: summary[n, c] = mean_p(pixel_positions) + MLP(coords)
__global__ __launch_bounds__(64) void k_summary(const float* __restrict__ pixpos,
                                                const float* __restrict__ w1,
                                                const float* __restrict__ b1,
                                                const float* __restrict__ w2,
                                                const float* __restrict__ b2,
                                                float* __restrict__ summary) {
    __shared__ float h[256];
    int n = blockIdx.x, t = threadIdx.x;  // 64 threads
    int rem = n & 1023;
    float cy = (float)(rem >> 5) * (1.f / 31.f);
    float cx = (float)(rem & 31) * (1.f / 31.f);
    for (int k = t; k < 256; k += 64) {
        float v = cy * w1[k] + cx * w1[256 + k] + b1[k];
        h[k] = v / (1.f + __expf(-v));   // silu
    }
    __syncthreads();
    float acc = b2[t];
    for (int k = 0; k < 256; ++k) acc += h[k] * w2[k * 64 + t];
    float pm = 0.f;
    for (int p = 0; p < 16; ++p) pm += pixpos[p * 64 + t];
    summary[n * 64 + t] = acc + pm * (1.f / 16.f);
}

// ---------------------------------------------------------------------------
// K3: per hyper-block: h1[n,256] = silu(summary @ wn_w1 + wn_b1) -> bf16
//                      bias[n,64] = silu(summary @ bn_w1 + bn_b1) @ bn_w2 + bn_b2
__global__ __launch_bounds__(256) void k_mlp(const float* __restrict__ summary,
                                             const float* __restrict__ w1w,
                                             const float* __restrict__ b1w,
                                             const float* __restrict__ w1b,
                                             const float* __restrict__ b1b,
                                             const float* __restrict__ w2b,
                                             const float* __restrict__ b2b,
                                             __hip_bfloat16* __restrict__ h1out,
                                             float* __restrict__ biasout) {
    __shared__ float ss[4][64];
    __shared__ float hb[4][257];
    int t = threadIdx.x;
    int n0 = blockIdx.x * 4;
    ss[t >> 6][t & 63] = summary[n0 * 64 + t];
    __syncthreads();
    float aw[4], ab[4];
    for (int g = 0; g < 4; ++g) { aw[g] = b1w[t]; ab[g] = b1b[t]; }
    for (int c = 0; c < 64; ++c) {
        float ww_ = w1w[c * 256 + t];
        float wb_ = w1b[c * 256 + t];
        for (int g = 0; g < 4; ++g) {
            aw[g] += ss[g][c] * ww_;
            ab[g] += ss[g][c] * wb_;
        }
    }
    for (int g = 0; g < 4; ++g) {
        float v = aw[g]; v = v / (1.f + __expf(-v));
        h1out[(n0 + g) * 256 + t] = __float2bfloat16(v);
        float u = ab[g]; u = u / (1.f + __expf(-u));
        hb[g][t] = u;
    }
    __syncthreads();
    {
        int g = t >> 6, c = t & 63;
        float acc = b2b[c];
        for (int k = 0; k < 256; ++k) acc += hb[g][k] * w2b[k * 64 + c];
        biasout[(n0 + g) * 64 + c] = acc;
    }
}

// ---------------------------------------------------------------------------
// K-cvt: transpose+convert wn_w2 [2][256][4096] f32 -> w2t [2][4096][256] bf16
__global__ __launch_bounds__(256) void k_w2t(const float* __restrict__ w2,
                                             __hip_bfloat16* __restrict__ w2t) {
    __shared__ float tile[64][65];
    int bid = blockIdx.x;          // 0..511
    int b = bid >> 8;
    int rem = bid & 255;
    int kt = rem >> 6;             // k0 = kt*64 (256/64 = 4)
    int nt = rem & 63;             // n0 = nt*64 (4096/64 = 64)
    int t = threadIdx.x;
    const float* src = w2 + (size_t)b * 256 * 4096 + (size_t)(kt * 64) * 4096 + nt * 64;
    for (int it = 0; it < 16; ++it) {
        int idx = t + it * 256;    // 64*64 = 4096
        int r = idx >> 6, c = idx & 63;
        tile[r][c] = src[(size_t)r * 4096 + c];
    }
    __syncthreads();
    __hip_bfloat16* dst = w2t + (size_t)b * 4096 * 256 + (size_t)(nt * 64) * 256 + kt * 64;
    for (int it = 0; it < 16; ++it) {
        int idx = t + it * 256;
        int rr = idx >> 6, cc = idx & 63;      // rr: n-local, cc: k-local
        dst[rr * 256 + cc] = __float2bfloat16(tile[cc][rr]);
    }
}

// ---------------------------------------------------------------------------
// K4: MFMA GEMM. wgt[m,n] = h1[m,:256] @ w2t[n,:256] + b2[n], bf16 out.
// M=8192, N=4096, K=256. 128x128 tile, BK=32, 4 waves, 16x16x32 bf16 MFMA.
// A-operand = w2t (rows n), B-operand = h1 (cols m) so D reg axis runs along n
// (vectorized 8B stores into wgt[m][n]).
__global__ __launch_bounds__(256) void k_wgt_mfma(const __hip_bfloat16* __restrict__ h1,
                                                  const __hip_bfloat16* __restrict__ w2t,
                                                  const float* __restrict__ b2,
                                                  __hip_bfloat16* __restrict__ wgt) {
    __shared__ short As[128 * 32];   // h1 tile  [m 128][k 32]
    __shared__ short Bs[128 * 32];   // w2t tile [n 128][k 32]
    int t = threadIdx.x;
    int l = t & 63, w = t >> 6;
    int mt = blockIdx.x & 63, nt = blockIdx.x >> 6;
    int m0 = mt << 7, n0 = nt << 7;
    int wr = w >> 1, wc = w & 1;     // wave quadrant: m-half, n-half
    int lrow = l & 15;
    int lk8 = (l >> 4) << 3;

    f32x4 acc[4][4] = {};            // [n-frag][m-frag]

    const char* gA = (const char*)(h1 + (size_t)m0 * 256);
    const char* gB = (const char*)(w2t + (size_t)n0 * 256);
    char* lA = (char*)As + (w << 10);   // wave-uniform base
    char* lB = (char*)Bs + (w << 10);

    for (int k0 = 0; k0 < 256; k0 += 32) {
        // stage A,B tiles: 512 chunks of 16B each, 2 chunks/thread/tile
        {
            int cid0 = t;
            int row0 = cid0 >> 2, ib0 = (cid0 & 3) << 3;
            GLOAD16(gA + ((size_t)row0 * 256 + k0 + ib0) * 2, lA);
            GLOAD16(gB + ((size_t)row0 * 256 + k0 + ib0) * 2, lB);
            int cid1 = 256 + t;
            int row1 = cid1 >> 2, ib1 = (cid1 & 3) << 3;
            GLOAD16(gA + ((size_t)row1 * 256 + k0 + ib1) * 2, lA + 4096);
            GLOAD16(gB + ((size_t)row1 * 256 + k0 + ib1) * 2, lB + 4096);
        }
        __syncthreads();
        short8v a[4], b[4];
        for (int i = 0; i < 4; ++i)
            a[i] = *(const short8v*)&Bs[(wc * 64 + i * 16 + lrow) * 32 + lk8];
        for (int j = 0; j < 4; ++j)
            b[j] = *(const short8v*)&As[(wr * 64 + j * 16 + lrow) * 32 + lk8];
        for (int i = 0; i < 4; ++i)
            for (int j = 0; j < 4; ++j)
                acc[i][j] = __builtin_amdgcn_mfma_f32_16x16x32_bf16(a[i], b[j], acc[i][j], 0, 0, 0);
        __syncthreads();
    }

    // epilogue: D row (reg axis) = n, D col (lane&15) = m
    for (int i = 0; i < 4; ++i) {
        int nb = n0 + wc * 64 + i * 16 + ((l >> 4) << 2);
        float4 bv = *(const float4*)&b2[nb];
        float bva[4] = {bv.x, bv.y, bv.z, bv.w};
        for (int j = 0; j < 4; ++j) {
            int m = m0 + wr * 64 + j * 16 + (l & 15);
            union { __hip_bfloat16 h[4]; uint2 u; } st;
            for (int r = 0; r < 4; ++r)
                st.h[r] = __float2bfloat16(acc[i][j][r] + bva[r]);
            *(uint2*)&wgt[(size_t)m * 4096 + nb] = st.u;
        }
    }
}

// ---------------------------------------------------------------------------
// K5: per patch: normed = LN(proc); proc = normed @ wgt^T + bias + proc  (in place)
__global__ __launch_bounds__(256) void k_bmm(float* __restrict__ proc,
                                             const __hip_bfloat16* __restrict__ wgt,
                                             const float* __restrict__ bias,
                                             const float* __restrict__ ln_g,
                                             const float* __restrict__ ln_b) {
    __shared__ float pr[16][64];
    __shared__ float nm[16][65];
    __shared__ float wg[64][65];
    __shared__ float bs[64];
    int n = blockIdx.x, t = threadIdx.x;
    for (int it = 0; it < 4; ++it) {
        int idx = t + it * 256;
        pr[idx >> 6][idx & 63] = proc[n * 1024 + idx];
    }
    if (t < 64) bs[t] = bias[n * 64 + t];
    // wgt row (4096 bf16) -> LDS floats
    for (int q = 0; q < 2; ++q) {
        int base = t * 16 + q * 8;
        union { uint4 u; unsigned short s[8]; } cv;
        cv.u = *(const uint4*)&wgt[(size_t)n * 4096 + base];
        int i = base >> 6, j = base & 63;
        for (int e = 0; e < 8; ++e) {
            unsigned int ub = ((unsigned int)cv.s[e]) << 16;
            wg[i][j + e] = __uint_as_float(ub);
        }
    }
    __syncthreads();
    // LayerNorm over channels (64) per token p
    {
        int p = t >> 4, lsub = t & 15;
        float s = 0.f, s2 = 0.f;
        for (int c = lsub; c < 64; c += 16) { float v = pr[p][c]; s += v; s2 += v * v; }
        for (int m = 1; m < 16; m <<= 1) { s += __shfl_xor(s, m); s2 += __shfl_xor(s2, m); }
        float mean = s * (1.f / 64.f);
        float var = s2 * (1.f / 64.f) - mean * mean;
        float rinv = rsqrtf(var + 1e-5f);
        for (int c = lsub; c < 64; c += 16)
            nm[p][c] = (pr[p][c] - mean) * rinv * ln_g[c] + ln_b[c];
    }
    __syncthreads();
    // out[p][i] = sum_j wg[i][j]*nm[p][j] + bs[i] + pr[p][i]
    {
        int p = t >> 4, il = t & 15;
        float o[4] = {0.f, 0.f, 0.f, 0.f};
        for (int j = 0; j < 64; ++j) {
            float nv = nm[p][j];
            o[0] += nv * wg[il][j];
            o[1] += nv * wg[il + 16][j];
            o[2] += nv * wg[il + 32][j];
            o[3] += nv * wg[il + 48][j];
        }
        for (int r = 0; r < 4; ++r) {
            int i = il + r * 16;
            proc[n * 1024 + p * 64 + i] = o[r] + bs[i] + pr[p][i];
        }
    }
}

// ---------------------------------------------------------------------------
// K6: 1x1 conv (64->256) + pixel shuffle r=2 -> out [8,64,256,256]
__global__ __launch_bounds__(256) void k_conv(const float* __restrict__ proc,
                                              const float* __restrict__ cw,
                                              const float* __restrict__ cb,
                                              float* __restrict__ out) {
    __shared__ float ms[64][132];   // merged[cc][w] for one (b,h) row
    int bid = blockIdx.x, t = threadIdx.x;
    int b = bid >> 7, h = bid & 127;
    int gy = h >> 2, py = h & 3;
    for (int it = 0; it < 32; ++it) {
        int idx = t + it * 256;          // w*64 + cc
        int w = idx >> 6, cc = idx & 63;
        int n = (b << 10) + (gy << 5) + (w >> 2);
        int p = (py << 2) + (w & 3);
        ms[cc][w] = proc[(n << 10) + (p << 6) + cc];
    }
    __syncthreads();
    int oc0 = (t & 31) * 8;
    for (int half = 0; half < 2; ++half) {
        int w0 = (t >> 5) * 8 + half * 64;
        float acc[8][8] = {};            // [w][oc]
        for (int cc = 0; cc < 64; ++cc) {
            float a[8], m8[8];
            *(float4*)(a)      = *(const float4*)&cw[cc * 256 + oc0];
            *(float4*)(a + 4)  = *(const float4*)&cw[cc * 256 + oc0 + 4];
            *(float4*)(m8)     = *(float4*)&ms[cc][w0];
            *(float4*)(m8 + 4) = *(float4*)&ms[cc][w0 + 4];
            for (int i = 0; i < 8; ++i)
                for (int j = 0; j < 8; ++j)
                    acc[i][j] += m8[i] * a[j];
        }
        for (int j = 0; j < 8; j += 2) {
            int oc = oc0 + j;
            int c = oc >> 2, s1 = (oc >> 1) & 1;
            float2* orow = (float2*)&out[(((size_t)b * 64 + c) * 256 + 2 * h + s1) * 256];
            float b0 = cb[oc], b1 = cb[oc + 1];
            for (int i = 0; i < 8; ++i)
                orow[w0 + i] = make_float2(acc[i][j] + b0, acc[i][j + 1] + b1);
        }
    }
}

// ---------------------------------------------------------------------------
extern "C" void kernel_launch(void* const* d_in, const int* in_sizes, int n_in,
                              void* d_out, int out_size, void* d_ws, size_t ws_size,
                              hipStream_t stream) {
    const float* x      = (const float*)d_in[0];
    const float* pixpos = (const float*)d_in[1];
    const float* ppe_w1 = (const float*)d_in[2];
    const float* ppe_b1 = (const float*)d_in[3];
    const float* ppe_w2 = (const float*)d_in[4];
    const float* ppe_b2 = (const float*)d_in[5];
    const float* ln_g   = (const float*)d_in[6];
    const float* ln_b   = (const float*)d_in[7];
    const float* wn_w1  = (const float*)d_in[8];
    const float* wn_b1  = (const float*)d_in[9];
    const float* wn_w2  = (const float*)d_in[10];
    const float* wn_b2  = (const float*)d_in[11];
    const float* bn_w1  = (const float*)d_in[12];
    const float* bn_b1  = (const float*)d_in[13];
    const float* bn_w2  = (const float*)d_in[14];
    const float* bn_b2  = (const float*)d_in[15];
    const float* conv_w = (const float*)d_in[16];
    const float* conv_b = (const float*)d_in[17];
    float* out = (float*)d_out;

    char* wsb = (char*)d_ws;
    float* proc    = (float*)wsb;  wsb += (size_t)NPAT * 1024 * 4;       // 32 MB
    float* summary = (float*)wsb;  wsb += (size_t)NPAT * 64 * 4;         //  2 MB
    __hip_bfloat16* h1 = (__hip_bfloat16*)wsb; wsb += (size_t)NPAT * 256 * 2;  // 4 MB
    float* bias    = (float*)wsb;  wsb += (size_t)NPAT * 64 * 4;         //  2 MB
    __hip_bfloat16* wgt = (__hip_bfloat16*)wsb; wsb += (size_t)NPAT * 4096 * 2; // 64 MB
    __hip_bfloat16* w2t = (__hip_bfloat16*)wsb;                          //  4 MB

    k_extract<<<32768, 256, 0, stream>>>(x, proc);
    k_summary<<<NPAT, 64, 0, stream>>>(pixpos, ppe_w1, ppe_b1, ppe_w2, ppe_b2, summary);
    k_w2t<<<512, 256, 0, stream>>>(wn_w2, w2t);
    for (int i = 0; i < 2; ++i) {
        k_mlp<<<NPAT / 4, 256, 0, stream>>>(summary,
                                            wn_w1 + (size_t)i * 64 * 256, wn_b1 + i * 256,
                                            bn_w1 + (size_t)i * 64 * 256, bn_b1 + i * 256,
                                            bn_w2 + (size_t)i * 256 * 64, bn_b2 + i * 64,
                                            h1, bias);
        k_wgt_mfma<<<2048, 256, 0, stream>>>(h1, w2t + (size_t)i * 4096 * 256,
                                             wn_b2 + (size_t)i * 4096, wgt);
        k_bmm<<<NPAT, 256, 0, stream>>>(proc, wgt, bias, ln_g + i * 64, ln_b + i * 64);
    }
    k_conv<<<1024, 256, 0, stream>>>(proc, conv_w, conv_b, out);
}

// Round 3
// 318.837 us; speedup vs baseline: 2.1806x; 1.2213x over previous
//
#include <hip/hip_runtime.h>
#include <hip/hip_bf16.h>

// Problem constants
constexpr int NPAT = 8192;     // B*PH*PW = 8*32*32

typedef __attribute__((ext_vector_type(8))) short short8v;   // 8 bf16
typedef __attribute__((ext_vector_type(4))) float f32x4;

#define GLOAD16(g, l) __builtin_amdgcn_global_load_lds( \
    (const __attribute__((address_space(1))) void*)(g), \
    (__attribute__((address_space(3))) void*)(l), 16, 0, 0)

__device__ inline short bf16s(float f) {
    __hip_bfloat16 h = __float2bfloat16(f);
    return *reinterpret_cast<short*>(&h);
}

// ---------------------------------------------------------------------------
// K1: unfold x [8,64,128,128] -> proc [8192,16,64]  (LDS transpose, coalesced)
__global__ __launch_bounds__(256) void k_extract(const float* __restrict__ x,
                                                 float* __restrict__ proc) {
    __shared__ float tile[64][129];
    int t = threadIdx.x;
    int b = blockIdx.x >> 7, h = blockIdx.x & 127;
    // read 64 channel-rows of 128 floats, coalesced
    for (int it = 0; it < 8; ++it) {
        int idx = it * 256 + t;
        int c = idx >> 5, w4 = (idx & 31) * 4;
        float4 v = *(const float4*)&x[(((size_t)b * 64 + c) * 128 + h) * 128 + w4];
        tile[c][w4] = v.x; tile[c][w4 + 1] = v.y;
        tile[c][w4 + 2] = v.z; tile[c][w4 + 3] = v.w;
    }
    __syncthreads();
    // write: each 64-lane group writes one pixel's 64-channel row (256B contiguous)
    int ny = (h >> 2) * 32, py = h & 3;
    for (int it = 0; it < 32; ++it) {
        int w = it * 4 + (t >> 6);
        int cc = t & 63;
        int n = (b << 10) + ny + (w >> 2);
        int p = (py << 2) + (w & 3);
        proc[((size_t)n << 10) + (p << 6) + cc] = tile[cc][w];
    }
}

// ---------------------------------------------------------------------------
// K2: summary[n, c] = mean_p(pixel_positions) + MLP(coords)
__global__ __launch_bounds__(64) void k_summary(const float* __restrict__ pixpos,
                                                const float* __restrict__ w1,
                                                const float* __restrict__ b1,
                                                const float* __restrict__ w2,
                                                const float* __restrict__ b2,
                                                float* __restrict__ summary) {
    __shared__ float h[256];
    int n = blockIdx.x, t = threadIdx.x;  // 64 threads
    int rem = n & 1023;
    float cy = (float)(rem >> 5) * (1.f / 31.f);
    float cx = (float)(rem & 31) * (1.f / 31.f);
    for (int k = t; k < 256; k += 64) {
        float v = cy * w1[k] + cx * w1[256 + k] + b1[k];
        h[k] = v / (1.f + __expf(-v));   // silu
    }
    __syncthreads();
    float acc = b2[t];
    for (int k = 0; k < 256; ++k) acc += h[k] * w2[k * 64 + t];
    float pm = 0.f;
    for (int p = 0; p < 16; ++p) pm += pixpos[p * 64 + t];
    summary[n * 64 + t] = acc + pm * (1.f / 16.f);
}

// ---------------------------------------------------------------------------
// K3: per hyper-block: h1[n,256] = silu(summary @ wn_w1 + wn_b1) -> bf16
//                      bias[n,64] = silu(summary @ bn_w1 + bn_b1) @ bn_w2 + bn_b2
__global__ __launch_bounds__(256) void k_mlp(const float* __restrict__ summary,
                                             const float* __restrict__ w1w,
                                             const float* __restrict__ b1w,
                                             const float* __restrict__ w1b,
                                             const float* __restrict__ b1b,
                                             const float* __restrict__ w2b,
                                             const float* __restrict__ b2b,
                                             __hip_bfloat16* __restrict__ h1out,
                                             float* __restrict__ biasout) {
    __shared__ float ss[4][64];
    __shared__ float hb[4][257];
    int t = threadIdx.x;
    int n0 = blockIdx.x * 4;
    ss[t >> 6][t & 63] = summary[n0 * 64 + t];
    __syncthreads();
    float aw[4], ab[4];
    for (int g = 0; g < 4; ++g) { aw[g] = b1w[t]; ab[g] = b1b[t]; }
    for (int c = 0; c < 64; ++c) {
        float ww_ = w1w[c * 256 + t];
        float wb_ = w1b[c * 256 + t];
        for (int g = 0; g < 4; ++g) {
            aw[g] += ss[g][c] * ww_;
            ab[g] += ss[g][c] * wb_;
        }
    }
    for (int g = 0; g < 4; ++g) {
        float v = aw[g]; v = v / (1.f + __expf(-v));
        h1out[(n0 + g) * 256 + t] = __float2bfloat16(v);
        float u = ab[g]; u = u / (1.f + __expf(-u));
        hb[g][t] = u;
    }
    __syncthreads();
    {
        int g = t >> 6, c = t & 63;
        float acc = b2b[c];
        for (int k = 0; k < 256; ++k) acc += hb[g][k] * w2b[k * 64 + c];
        biasout[(n0 + g) * 64 + c] = acc;
    }
}

// ---------------------------------------------------------------------------
// K-cvt: transpose+convert wn_w2 [2][256][4096] f32 -> w2t [2][4096][256] bf16
__global__ __launch_bounds__(256) void k_w2t(const float* __restrict__ w2,
                                             __hip_bfloat16* __restrict__ w2t) {
    __shared__ float tile[64][65];
    int bid = blockIdx.x;          // 0..511
    int b = bid >> 8;
    int rem = bid & 255;
    int kt = rem >> 6;             // k0 = kt*64 (256/64 = 4)
    int nt = rem & 63;             // n0 = nt*64 (4096/64 = 64)
    int t = threadIdx.x;
    const float* src = w2 + (size_t)b * 256 * 4096 + (size_t)(kt * 64) * 4096 + nt * 64;
    for (int it = 0; it < 16; ++it) {
        int idx = t + it * 256;    // 64*64 = 4096
        int r = idx >> 6, c = idx & 63;
        tile[r][c] = src[(size_t)r * 4096 + c];
    }
    __syncthreads();
    __hip_bfloat16* dst = w2t + (size_t)b * 4096 * 256 + (size_t)(nt * 64) * 256 + kt * 64;
    for (int it = 0; it < 16; ++it) {
        int idx = t + it * 256;
        int rr = idx >> 6, cc = idx & 63;      // rr: n-local, cc: k-local
        dst[rr * 256 + cc] = __float2bfloat16(tile[cc][rr]);
    }
}

// ---------------------------------------------------------------------------
// K-cvt2: conv_w [64][256] f32 -> cwt_g [256 oc][64 cc] bf16, XOR-pre-swizzled
// rows of 128B: chunk q (of 8x16B) stored at slot q^(oc&7).
__global__ __launch_bounds__(256) void k_cwt(const float* __restrict__ cw,
                                             __hip_bfloat16* __restrict__ cwt_g) {
    int idx = blockIdx.x * 256 + threadIdx.x;   // 0..16383
    int oc = idx >> 6, cc = idx & 63;
    float v = cw[cc * 256 + oc];
    int el = oc * 64 + (((cc >> 3) ^ (oc & 7)) << 3) + (cc & 7);
    cwt_g[el] = __float2bfloat16(v);
}

// ---------------------------------------------------------------------------
// K4: MFMA GEMM. wgt[m,n] = h1[m,:256] @ w2t[n,:256] + b2[n], bf16 out.
__global__ __launch_bounds__(256) void k_wgt_mfma(const __hip_bfloat16* __restrict__ h1,
                                                  const __hip_bfloat16* __restrict__ w2t,
                                                  const float* __restrict__ b2,
                                                  __hip_bfloat16* __restrict__ wgt) {
    __shared__ short As[128 * 32];   // h1 tile  [m 128][k 32]
    __shared__ short Bs[128 * 32];   // w2t tile [n 128][k 32]
    int t = threadIdx.x;
    int l = t & 63, w = t >> 6;
    int mt = blockIdx.x & 63, nt = blockIdx.x >> 6;
    int m0 = mt << 7, n0 = nt << 7;
    int wr = w >> 1, wc = w & 1;     // wave quadrant: m-half, n-half
    int lrow = l & 15;
    int lk8 = (l >> 4) << 3;

    f32x4 acc[4][4] = {};            // [n-frag][m-frag]

    const char* gA = (const char*)(h1 + (size_t)m0 * 256);
    const char* gB = (const char*)(w2t + (size_t)n0 * 256);
    char* lA = (char*)As + (w << 10);   // wave-uniform base
    char* lB = (char*)Bs + (w << 10);

    for (int k0 = 0; k0 < 256; k0 += 32) {
        {
            int cid0 = t;
            int row0 = cid0 >> 2, ib0 = (cid0 & 3) << 3;
            GLOAD16(gA + ((size_t)row0 * 256 + k0 + ib0) * 2, lA);
            GLOAD16(gB + ((size_t)row0 * 256 + k0 + ib0) * 2, lB);
            int cid1 = 256 + t;
            int row1 = cid1 >> 2, ib1 = (cid1 & 3) << 3;
            GLOAD16(gA + ((size_t)row1 * 256 + k0 + ib1) * 2, lA + 4096);
            GLOAD16(gB + ((size_t)row1 * 256 + k0 + ib1) * 2, lB + 4096);
        }
        __syncthreads();
        short8v a[4], b[4];
        for (int i = 0; i < 4; ++i)
            a[i] = *(const short8v*)&Bs[(wc * 64 + i * 16 + lrow) * 32 + lk8];
        for (int j = 0; j < 4; ++j)
            b[j] = *(const short8v*)&As[(wr * 64 + j * 16 + lrow) * 32 + lk8];
        for (int i = 0; i < 4; ++i)
            for (int j = 0; j < 4; ++j)
                acc[i][j] = __builtin_amdgcn_mfma_f32_16x16x32_bf16(a[i], b[j], acc[i][j], 0, 0, 0);
        __syncthreads();
    }

    for (int i = 0; i < 4; ++i) {
        int nb = n0 + wc * 64 + i * 16 + ((l >> 4) << 2);
        float4 bv = *(const float4*)&b2[nb];
        float bva[4] = {bv.x, bv.y, bv.z, bv.w};
        for (int j = 0; j < 4; ++j) {
            int m = m0 + wr * 64 + j * 16 + (l & 15);
            union { __hip_bfloat16 h[4]; uint2 u; } st;
            for (int r = 0; r < 4; ++r)
                st.h[r] = __float2bfloat16(acc[i][j][r] + bva[r]);
            *(uint2*)&wgt[(size_t)m * 4096 + nb] = st.u;
        }
    }
}

// ---------------------------------------------------------------------------
// K5: per patch: normed = LN(proc); proc = normed @ wgt^T + bias + proc  (in place)
__global__ __launch_bounds__(256) void k_bmm(float* __restrict__ proc,
                                             const __hip_bfloat16* __restrict__ wgt,
                                             const float* __restrict__ bias,
                                             const float* __restrict__ ln_g,
                                             const float* __restrict__ ln_b) {
    __shared__ float pr[16][64];
    __shared__ float nm[16][65];
    __shared__ float wg[64][65];
    __shared__ float bs[64];
    int n = blockIdx.x, t = threadIdx.x;
    for (int it = 0; it < 4; ++it) {
        int idx = t + it * 256;
        pr[idx >> 6][idx & 63] = proc[n * 1024 + idx];
    }
    if (t < 64) bs[t] = bias[n * 64 + t];
    for (int q = 0; q < 2; ++q) {
        int base = t * 16 + q * 8;
        union { uint4 u; unsigned short s[8]; } cv;
        cv.u = *(const uint4*)&wgt[(size_t)n * 4096 + base];
        int i = base >> 6, j = base & 63;
        for (int e = 0; e < 8; ++e) {
            unsigned int ub = ((unsigned int)cv.s[e]) << 16;
            wg[i][j + e] = __uint_as_float(ub);
        }
    }
    __syncthreads();
    {
        int p = t >> 4, lsub = t & 15;
        float s = 0.f, s2 = 0.f;
        for (int c = lsub; c < 64; c += 16) { float v = pr[p][c]; s += v; s2 += v * v; }
        for (int m = 1; m < 16; m <<= 1) { s += __shfl_xor(s, m); s2 += __shfl_xor(s2, m); }
        float mean = s * (1.f / 64.f);
        float var = s2 * (1.f / 64.f) - mean * mean;
        float rinv = rsqrtf(var + 1e-5f);
        for (int c = lsub; c < 64; c += 16)
            nm[p][c] = (pr[p][c] - mean) * rinv * ln_g[c] + ln_b[c];
    }
    __syncthreads();
    {
        int p = t >> 4, il = t & 15;
        float o[4] = {0.f, 0.f, 0.f, 0.f};
        for (int j = 0; j < 64; ++j) {
            float nv = nm[p][j];
            o[0] += nv * wg[il][j];
            o[1] += nv * wg[il + 16][j];
            o[2] += nv * wg[il + 32][j];
            o[3] += nv * wg[il + 48][j];
        }
        for (int r = 0; r < 4; ++r) {
            int i = il + r * 16;
            proc[n * 1024 + p * 64 + i] = o[r] + bs[i] + pr[p][i];
        }
    }
}

// ---------------------------------------------------------------------------
// K6: 1x1 conv (64->256) + pixel shuffle, MFMA version.
// Per block: (b, hh) row. out tile [256 oc][128 w] = cwt[oc][cc] @ ms[w][cc]^T.
__global__ __launch_bounds__(256) void k_conv_mfma(const float* __restrict__ proc,
                                                   const __hip_bfloat16* __restrict__ cwt_g,
                                                   const float* __restrict__ cb,
                                                   float* __restrict__ out) {
    __shared__ short cwt[256 * 64];   // [oc][cc] bf16, 128B rows, XOR-swizzled
    __shared__ short msb[128 * 64];   // [w][cc]  bf16, 128B rows, XOR-swizzled
    __shared__ float cbl[256];
    int t = threadIdx.x;
    int l = t & 63, wv = t >> 6;
    int b = blockIdx.x >> 7, hh = blockIdx.x & 127;

    // stage cwt (pre-swizzled in global) via global_load_lds, linear
    for (int it = 0; it < 8; ++it) {
        int cid0 = it * 256 + wv * 64;
        GLOAD16((const char*)cwt_g + ((size_t)(cid0 + l) << 4),
                (char*)cwt + ((size_t)cid0 << 4));
    }
    cbl[t] = cb[t];
    // stage merged tile: reg-staged f32->bf16, swizzled ds_write
    int ny = (hh >> 2) * 32, py = hh & 3;
    for (int it = 0; it < 4; ++it) {
        int cid = it * 256 + t;
        int w = cid >> 3, q = cid & 7;
        int n = (b << 10) + ny + (w >> 2);
        int p = (py << 2) + (w & 3);
        const float* src = proc + ((size_t)n << 10) + (p << 6) + q * 8;
        float4 v0 = *(const float4*)src;
        float4 v1 = *(const float4*)(src + 4);
        short8v sv;
        sv[0] = bf16s(v0.x); sv[1] = bf16s(v0.y); sv[2] = bf16s(v0.z); sv[3] = bf16s(v0.w);
        sv[4] = bf16s(v1.x); sv[5] = bf16s(v1.y); sv[6] = bf16s(v1.z); sv[7] = bf16s(v1.w);
        *(short8v*)&msb[w * 64 + (((q ^ (w & 7))) << 3)] = sv;
    }
    __syncthreads();

    int wvo = wv >> 1, wvw = wv & 1;
    int lrow = l & 15, lhi = l >> 4;
    f32x4 acc[8][4] = {};    // [oc-frag][w-frag]
    for (int ks = 0; ks < 2; ++ks) {
        int q = ks * 4 + lhi;   // k-chunk 0..7
        short8v a[8], bb[4];
        for (int i = 0; i < 8; ++i) {
            int ocr = wvo * 128 + i * 16 + lrow;
            a[i] = *(const short8v*)((const char*)cwt + ocr * 128 + ((q ^ (ocr & 7)) << 4));
        }
        for (int j = 0; j < 4; ++j) {
            int wr = wvw * 64 + j * 16 + lrow;
            bb[j] = *(const short8v*)((const char*)msb + wr * 128 + ((q ^ (wr & 7)) << 4));
        }
        for (int i = 0; i < 8; ++i)
            for (int j = 0; j < 4; ++j)
                acc[i][j] = __builtin_amdgcn_mfma_f32_16x16x32_bf16(a[i], bb[j], acc[i][j], 0, 0, 0);
    }

    // epilogue: oc = wvo*128 + i*16 + lhi*4 + r ; w = wvw*64 + j*16 + lrow
    // out[b][c][2hh+r1][2w+r2], oc = c*4 + r1*2 + r2 -> regs (0,1)->row0, (2,3)->row1
    for (int i = 0; i < 8; ++i) {
        int oc4 = wvo * 128 + i * 16 + lhi * 4;
        int c = oc4 >> 2;
        float cb0 = cbl[oc4], cb1 = cbl[oc4 + 1], cb2 = cbl[oc4 + 2], cb3 = cbl[oc4 + 3];
        float* row0 = out + (((size_t)b * 64 + c) * 256 + 2 * hh) * 256;
        float* row1 = row0 + 256;
        for (int j = 0; j < 4; ++j) {
            int w = wvw * 64 + j * 16 + lrow;
            ((float2*)row0)[w] = make_float2(acc[i][j][0] + cb0, acc[i][j][1] + cb1);
            ((float2*)row1)[w] = make_float2(acc[i][j][2] + cb2, acc[i][j][3] + cb3);
        }
    }
}

// ---------------------------------------------------------------------------
extern "C" void kernel_launch(void* const* d_in, const int* in_sizes, int n_in,
                              void* d_out, int out_size, void* d_ws, size_t ws_size,
                              hipStream_t stream) {
    const float* x      = (const float*)d_in[0];
    const float* pixpos = (const float*)d_in[1];
    const float* ppe_w1 = (const float*)d_in[2];
    const float* ppe_b1 = (const float*)d_in[3];
    const float* ppe_w2 = (const float*)d_in[4];
    const float* ppe_b2 = (const float*)d_in[5];
    const float* ln_g   = (const float*)d_in[6];
    const float* ln_b   = (const float*)d_in[7];
    const float* wn_w1  = (const float*)d_in[8];
    const float* wn_b1  = (const float*)d_in[9];
    const float* wn_w2  = (const float*)d_in[10];
    const float* wn_b2  = (const float*)d_in[11];
    const float* bn_w1  = (const float*)d_in[12];
    const float* bn_b1  = (const float*)d_in[13];
    const float* bn_w2  = (const float*)d_in[14];
    const float* bn_b2  = (const float*)d_in[15];
    const float* conv_w = (const float*)d_in[16];
    const float* conv_b = (const float*)d_in[17];
    float* out = (float*)d_out;

    char* wsb = (char*)d_ws;
    float* proc    = (float*)wsb;  wsb += (size_t)NPAT * 1024 * 4;       // 32 MB
    float* summary = (float*)wsb;  wsb += (size_t)NPAT * 64 * 4;         //  2 MB
    __hip_bfloat16* h1 = (__hip_bfloat16*)wsb; wsb += (size_t)NPAT * 256 * 2;  // 4 MB
    float* bias    = (float*)wsb;  wsb += (size_t)NPAT * 64 * 4;         //  2 MB
    __hip_bfloat16* wgt = (__hip_bfloat16*)wsb; wsb += (size_t)NPAT * 4096 * 2; // 64 MB
    __hip_bfloat16* w2t = (__hip_bfloat16*)wsb; wsb += (size_t)2 * 4096 * 256 * 2; // 4 MB
    __hip_bfloat16* cwt_g = (__hip_bfloat16*)wsb;                        // 32 KB

    k_extract<<<1024, 256, 0, stream>>>(x, proc);
    k_summary<<<NPAT, 64, 0, stream>>>(pixpos, ppe_w1, ppe_b1, ppe_w2, ppe_b2, summary);
    k_w2t<<<512, 256, 0, stream>>>(wn_w2, w2t);
    k_cwt<<<64, 256, 0, stream>>>(conv_w, cwt_g);
    for (int i = 0; i < 2; ++i) {
        k_mlp<<<NPAT / 4, 256, 0, stream>>>(summary,
                                            wn_w1 + (size_t)i * 64 * 256, wn_b1 + i * 256,
                                            bn_w1 + (size_t)i * 64 * 256, bn_b1 + i * 256,
                                            bn_w2 + (size_t)i * 256 * 64, bn_b2 + i * 64,
                                            h1, bias);
        k_wgt_mfma<<<2048, 256, 0, stream>>>(h1, w2t + (size_t)i * 4096 * 256,
                                             wn_b2 + (size_t)i * 4096, wgt);
        k_bmm<<<NPAT, 256, 0, stream>>>(proc, wgt, bias, ln_g + i * 64, ln_b + i * 64);
    }
    k_conv_mfma<<<1024, 256, 0, stream>>>(proc, cwt_g, conv_b, out);
}

// Round 4
// 264.514 us; speedup vs baseline: 2.6284x; 1.2054x over previous
//
#include <hip/hip_runtime.h>
#include <hip/hip_bf16.h>

// Problem constants
constexpr int NPAT = 8192;     // B*PH*PW = 8*32*32

typedef __attribute__((ext_vector_type(8))) short short8v;   // 8 bf16
typedef __attribute__((ext_vector_type(4))) float f32x4;

#define GLOAD16(g, l) __builtin_amdgcn_global_load_lds( \
    (const __attribute__((address_space(1))) void*)(g), \
    (__attribute__((address_space(3))) void*)(l), 16, 0, 0)

__device__ inline short bf16s(float f) {
    __hip_bfloat16 h = __float2bfloat16(f);
    return *reinterpret_cast<short*>(&h);
}

// ---------------------------------------------------------------------------
// K1: unfold x [8,64,128,128] -> proc [8192,16,64]  (LDS transpose, coalesced)
__global__ __launch_bounds__(256) void k_extract(const float* __restrict__ x,
                                                 float* __restrict__ proc) {
    __shared__ float tile[64][129];
    int t = threadIdx.x;
    int b = blockIdx.x >> 7, h = blockIdx.x & 127;
    for (int it = 0; it < 8; ++it) {
        int idx = it * 256 + t;
        int c = idx >> 5, w4 = (idx & 31) * 4;
        float4 v = *(const float4*)&x[(((size_t)b * 64 + c) * 128 + h) * 128 + w4];
        tile[c][w4] = v.x; tile[c][w4 + 1] = v.y;
        tile[c][w4 + 2] = v.z; tile[c][w4 + 3] = v.w;
    }
    __syncthreads();
    int ny = (h >> 2) * 32, py = h & 3;
    for (int it = 0; it < 32; ++it) {
        int w = it * 4 + (t >> 6);
        int cc = t & 63;
        int n = (b << 10) + ny + (w >> 2);
        int p = (py << 2) + (w & 3);
        proc[((size_t)n << 10) + (p << 6) + cc] = tile[cc][w];
    }
}

// ---------------------------------------------------------------------------
// K2: summary[n, c] = mean_p(pixel_positions) + MLP(coords)
__global__ __launch_bounds__(64) void k_summary(const float* __restrict__ pixpos,
                                                const float* __restrict__ w1,
                                                const float* __restrict__ b1,
                                                const float* __restrict__ w2,
                                                const float* __restrict__ b2,
                                                float* __restrict__ summary) {
    __shared__ float h[256];
    int n = blockIdx.x, t = threadIdx.x;  // 64 threads
    int rem = n & 1023;
    float cy = (float)(rem >> 5) * (1.f / 31.f);
    float cx = (float)(rem & 31) * (1.f / 31.f);
    for (int k = t; k < 256; k += 64) {
        float v = cy * w1[k] + cx * w1[256 + k] + b1[k];
        h[k] = v / (1.f + __expf(-v));   // silu
    }
    __syncthreads();
    float acc = b2[t];
    for (int k = 0; k < 256; ++k) acc += h[k] * w2[k * 64 + t];
    float pm = 0.f;
    for (int p = 0; p < 16; ++p) pm += pixpos[p * 64 + t];
    summary[n * 64 + t] = acc + pm * (1.f / 16.f);
}

// ---------------------------------------------------------------------------
// K3: per hyper-block: h1[n,256] = silu(summary @ wn_w1 + wn_b1) -> bf16
//                      bias[n,64] = silu(summary @ bn_w1 + bn_b1) @ bn_w2 + bn_b2
__global__ __launch_bounds__(256) void k_mlp(const float* __restrict__ summary,
                                             const float* __restrict__ w1w,
                                             const float* __restrict__ b1w,
                                             const float* __restrict__ w1b,
                                             const float* __restrict__ b1b,
                                             const float* __restrict__ w2b,
                                             const float* __restrict__ b2b,
                                             __hip_bfloat16* __restrict__ h1out,
                                             float* __restrict__ biasout) {
    __shared__ float ss[4][64];
    __shared__ float hb[4][257];
    int t = threadIdx.x;
    int n0 = blockIdx.x * 4;
    ss[t >> 6][t & 63] = summary[n0 * 64 + t];
    __syncthreads();
    float aw[4], ab[4];
    for (int g = 0; g < 4; ++g) { aw[g] = b1w[t]; ab[g] = b1b[t]; }
    for (int c = 0; c < 64; ++c) {
        float ww_ = w1w[c * 256 + t];
        float wb_ = w1b[c * 256 + t];
        for (int g = 0; g < 4; ++g) {
            aw[g] += ss[g][c] * ww_;
            ab[g] += ss[g][c] * wb_;
        }
    }
    for (int g = 0; g < 4; ++g) {
        float v = aw[g]; v = v / (1.f + __expf(-v));
        h1out[(n0 + g) * 256 + t] = __float2bfloat16(v);
        float u = ab[g]; u = u / (1.f + __expf(-u));
        hb[g][t] = u;
    }
    __syncthreads();
    {
        int g = t >> 6, c = t & 63;
        float acc = b2b[c];
        for (int k = 0; k < 256; ++k) acc += hb[g][k] * w2b[k * 64 + c];
        biasout[(n0 + g) * 64 + c] = acc;
    }
}

// ---------------------------------------------------------------------------
// K-cvt: transpose+convert wn_w2 [2][256][4096] f32 -> w2t [2][4096][256] bf16
__global__ __launch_bounds__(256) void k_w2t(const float* __restrict__ w2,
                                             __hip_bfloat16* __restrict__ w2t) {
    __shared__ float tile[64][65];
    int bid = blockIdx.x;          // 0..511
    int b = bid >> 8;
    int rem = bid & 255;
    int kt = rem >> 6;
    int nt = rem & 63;
    int t = threadIdx.x;
    const float* src = w2 + (size_t)b * 256 * 4096 + (size_t)(kt * 64) * 4096 + nt * 64;
    for (int it = 0; it < 16; ++it) {
        int idx = t + it * 256;
        int r = idx >> 6, c = idx & 63;
        tile[r][c] = src[(size_t)r * 4096 + c];
    }
    __syncthreads();
    __hip_bfloat16* dst = w2t + (size_t)b * 4096 * 256 + (size_t)(nt * 64) * 256 + kt * 64;
    for (int it = 0; it < 16; ++it) {
        int idx = t + it * 256;
        int rr = idx >> 6, cc = idx & 63;
        dst[rr * 256 + cc] = __float2bfloat16(tile[cc][rr]);
    }
}

// ---------------------------------------------------------------------------
// K-cvt2: conv_w [64][256] f32 -> cwt_g [256 oc][64 cc] bf16, XOR-pre-swizzled
__global__ __launch_bounds__(256) void k_cwt(const float* __restrict__ cw,
                                             __hip_bfloat16* __restrict__ cwt_g) {
    int idx = blockIdx.x * 256 + threadIdx.x;   // 0..16383
    int oc = idx >> 6, cc = idx & 63;
    float v = cw[cc * 256 + oc];
    int el = oc * 64 + (((cc >> 3) ^ (oc & 7)) << 3) + (cc & 7);
    cwt_g[el] = __float2bfloat16(v);
}

// ---------------------------------------------------------------------------
// K4: MFMA GEMM. wgt[m,n] = h1[m,:256] @ w2t[n,:256] + b2[n], bf16 out.
__global__ __launch_bounds__(256) void k_wgt_mfma(const __hip_bfloat16* __restrict__ h1,
                                                  const __hip_bfloat16* __restrict__ w2t,
                                                  const float* __restrict__ b2,
                                                  __hip_bfloat16* __restrict__ wgt) {
    __shared__ short As[128 * 32];
    __shared__ short Bs[128 * 32];
    int t = threadIdx.x;
    int l = t & 63, w = t >> 6;
    int mt = blockIdx.x & 63, nt = blockIdx.x >> 6;
    int m0 = mt << 7, n0 = nt << 7;
    int wr = w >> 1, wc = w & 1;
    int lrow = l & 15;
    int lk8 = (l >> 4) << 3;

    f32x4 acc[4][4] = {};

    const char* gA = (const char*)(h1 + (size_t)m0 * 256);
    const char* gB = (const char*)(w2t + (size_t)n0 * 256);
    char* lA = (char*)As + (w << 10);
    char* lB = (char*)Bs + (w << 10);

    for (int k0 = 0; k0 < 256; k0 += 32) {
        {
            int cid0 = t;
            int row0 = cid0 >> 2, ib0 = (cid0 & 3) << 3;
            GLOAD16(gA + ((size_t)row0 * 256 + k0 + ib0) * 2, lA);
            GLOAD16(gB + ((size_t)row0 * 256 + k0 + ib0) * 2, lB);
            int cid1 = 256 + t;
            int row1 = cid1 >> 2, ib1 = (cid1 & 3) << 3;
            GLOAD16(gA + ((size_t)row1 * 256 + k0 + ib1) * 2, lA + 4096);
            GLOAD16(gB + ((size_t)row1 * 256 + k0 + ib1) * 2, lB + 4096);
        }
        __syncthreads();
        short8v a[4], b[4];
        for (int i = 0; i < 4; ++i)
            a[i] = *(const short8v*)&Bs[(wc * 64 + i * 16 + lrow) * 32 + lk8];
        for (int j = 0; j < 4; ++j)
            b[j] = *(const short8v*)&As[(wr * 64 + j * 16 + lrow) * 32 + lk8];
        for (int i = 0; i < 4; ++i)
            for (int j = 0; j < 4; ++j)
                acc[i][j] = __builtin_amdgcn_mfma_f32_16x16x32_bf16(a[i], b[j], acc[i][j], 0, 0, 0);
        __syncthreads();
    }

    for (int i = 0; i < 4; ++i) {
        int nb = n0 + wc * 64 + i * 16 + ((l >> 4) << 2);
        float4 bv = *(const float4*)&b2[nb];
        float bva[4] = {bv.x, bv.y, bv.z, bv.w};
        for (int j = 0; j < 4; ++j) {
            int m = m0 + wr * 64 + j * 16 + (l & 15);
            union { __hip_bfloat16 h[4]; uint2 u; } st;
            for (int r = 0; r < 4; ++r)
                st.h[r] = __float2bfloat16(acc[i][j][r] + bva[r]);
            *(uint2*)&wgt[(size_t)m * 4096 + nb] = st.u;
        }
    }
}

// ---------------------------------------------------------------------------
// K5 (MFMA): per patch (one wave): nm = LN(proc); proc += wgt @ nm^T + bias.
// D[i,p] = sum_j wgt[i,j] * nm[p,j].  8x mfma_f32_16x16x32_bf16 per wave.
__global__ __launch_bounds__(256) void k_bmm(float* __restrict__ proc,
                                             const __hip_bfloat16* __restrict__ wgt,
                                             const float* __restrict__ bias,
                                             const float* __restrict__ ln_g,
                                             const float* __restrict__ ln_b) {
    __shared__ short nm_lds[4][16][72];   // per-wave [token][chan] bf16, pad 72
    int t = threadIdx.x;
    int w = t >> 6, l = t & 63;
    int n = blockIdx.x * 4 + w;
    int p = l & 15, hi = l >> 4;          // token, channel-quarter

    // ---- load 16 channels (hi*16..) of token p, fp32
    const float* prow = proc + ((size_t)n << 10) + (p << 6) + (hi << 4);
    float pr[16];
    *(float4*)(pr)      = *(const float4*)(prow);
    *(float4*)(pr + 4)  = *(const float4*)(prow + 4);
    *(float4*)(pr + 8)  = *(const float4*)(prow + 8);
    *(float4*)(pr + 12) = *(const float4*)(prow + 12);

    // ---- LN stats across the 4 lanes holding token p
    float s = 0.f, s2 = 0.f;
    for (int i = 0; i < 16; ++i) { s += pr[i]; s2 += pr[i] * pr[i]; }
    s += __shfl_xor(s, 16);  s2 += __shfl_xor(s2, 16);
    s += __shfl_xor(s, 32);  s2 += __shfl_xor(s2, 32);
    float mean = s * (1.f / 64.f);
    float var = s2 * (1.f / 64.f) - mean * mean;
    float rinv = rsqrtf(var + 1e-5f);

    // ---- normalize, convert bf16, stage to LDS
    float gg[16], bb_[16];
    {
        const float* gp = ln_g + (hi << 4);
        const float* bp = ln_b + (hi << 4);
        *(float4*)(gg)      = *(const float4*)(gp);
        *(float4*)(gg + 4)  = *(const float4*)(gp + 4);
        *(float4*)(gg + 8)  = *(const float4*)(gp + 8);
        *(float4*)(gg + 12) = *(const float4*)(gp + 12);
        *(float4*)(bb_)      = *(const float4*)(bp);
        *(float4*)(bb_ + 4)  = *(const float4*)(bp + 4);
        *(float4*)(bb_ + 8)  = *(const float4*)(bp + 8);
        *(float4*)(bb_ + 12) = *(const float4*)(bp + 12);
    }
    short8v nm0, nm1;
    for (int i = 0; i < 8; ++i)
        nm0[i] = bf16s((pr[i] - mean) * rinv * gg[i] + bb_[i]);
    for (int i = 0; i < 8; ++i)
        nm1[i] = bf16s((pr[8 + i] - mean) * rinv * gg[8 + i] + bb_[8 + i]);
    *(short8v*)&nm_lds[w][p][hi * 16]     = nm0;
    *(short8v*)&nm_lds[w][p][hi * 16 + 8] = nm1;
    __syncthreads();

    // ---- A-fragments straight from global wgt row (bf16)
    const __hip_bfloat16* wrow = wgt + ((size_t)n << 12);
    short8v af[4][2];
    for (int ib = 0; ib < 4; ++ib)
        for (int ks = 0; ks < 2; ++ks)
            af[ib][ks] = *(const short8v*)&wrow[(ib * 16 + p) * 64 + ks * 32 + hi * 8];

    // ---- B-fragments from LDS
    short8v bf0 = *(const short8v*)&nm_lds[w][p][hi * 8];
    short8v bf1 = *(const short8v*)&nm_lds[w][p][32 + hi * 8];

    // ---- 8 MFMA
    f32x4 acc[4] = {};
    for (int ib = 0; ib < 4; ++ib) {
        acc[ib] = __builtin_amdgcn_mfma_f32_16x16x32_bf16(af[ib][0], bf0, acc[ib], 0, 0, 0);
        acc[ib] = __builtin_amdgcn_mfma_f32_16x16x32_bf16(af[ib][1], bf1, acc[ib], 0, 0, 0);
    }

    // ---- epilogue: proc[p][i] += D[i][p] + bias[i]
    float* orow = proc + ((size_t)n << 10) + (p << 6);
    const float* brow = bias + ((size_t)n << 6);
    for (int ib = 0; ib < 4; ++ib) {
        int i0 = ib * 16 + hi * 4;
        float4 res = *(const float4*)&orow[i0];
        float4 bsv = *(const float4*)&brow[i0];
        float4 o;
        o.x = acc[ib][0] + bsv.x + res.x;
        o.y = acc[ib][1] + bsv.y + res.y;
        o.z = acc[ib][2] + bsv.z + res.z;
        o.w = acc[ib][3] + bsv.w + res.w;
        *(float4*)&orow[i0] = o;
    }
}

// ---------------------------------------------------------------------------
// K6: 1x1 conv (64->256) + pixel shuffle, MFMA version.
__global__ __launch_bounds__(256) void k_conv_mfma(const float* __restrict__ proc,
                                                   const __hip_bfloat16* __restrict__ cwt_g,
                                                   const float* __restrict__ cb,
                                                   float* __restrict__ out) {
    __shared__ short cwt[256 * 64];
    __shared__ short msb[128 * 64];
    __shared__ float cbl[256];
    int t = threadIdx.x;
    int l = t & 63, wv = t >> 6;
    int b = blockIdx.x >> 7, hh = blockIdx.x & 127;

    for (int it = 0; it < 8; ++it) {
        int cid0 = it * 256 + wv * 64;
        GLOAD16((const char*)cwt_g + ((size_t)(cid0 + l) << 4),
                (char*)cwt + ((size_t)cid0 << 4));
    }
    cbl[t] = cb[t];
    int ny = (hh >> 2) * 32, py = hh & 3;
    for (int it = 0; it < 4; ++it) {
        int cid = it * 256 + t;
        int w = cid >> 3, q = cid & 7;
        int n = (b << 10) + ny + (w >> 2);
        int p = (py << 2) + (w & 3);
        const float* src = proc + ((size_t)n << 10) + (p << 6) + q * 8;
        float4 v0 = *(const float4*)src;
        float4 v1 = *(const float4*)(src + 4);
        short8v sv;
        sv[0] = bf16s(v0.x); sv[1] = bf16s(v0.y); sv[2] = bf16s(v0.z); sv[3] = bf16s(v0.w);
        sv[4] = bf16s(v1.x); sv[5] = bf16s(v1.y); sv[6] = bf16s(v1.z); sv[7] = bf16s(v1.w);
        *(short8v*)&msb[w * 64 + (((q ^ (w & 7))) << 3)] = sv;
    }
    __syncthreads();

    int wvo = wv >> 1, wvw = wv & 1;
    int lrow = l & 15, lhi = l >> 4;
    f32x4 acc[8][4] = {};
    for (int ks = 0; ks < 2; ++ks) {
        int q = ks * 4 + lhi;
        short8v a[8], bb[4];
        for (int i = 0; i < 8; ++i) {
            int ocr = wvo * 128 + i * 16 + lrow;
            a[i] = *(const short8v*)((const char*)cwt + ocr * 128 + ((q ^ (ocr & 7)) << 4));
        }
        for (int j = 0; j < 4; ++j) {
            int wr = wvw * 64 + j * 16 + lrow;
            bb[j] = *(const short8v*)((const char*)msb + wr * 128 + ((q ^ (wr & 7)) << 4));
        }
        for (int i = 0; i < 8; ++i)
            for (int j = 0; j < 4; ++j)
                acc[i][j] = __builtin_amdgcn_mfma_f32_16x16x32_bf16(a[i], bb[j], acc[i][j], 0, 0, 0);
    }

    for (int i = 0; i < 8; ++i) {
        int oc4 = wvo * 128 + i * 16 + lhi * 4;
        int c = oc4 >> 2;
        float cb0 = cbl[oc4], cb1 = cbl[oc4 + 1], cb2 = cbl[oc4 + 2], cb3 = cbl[oc4 + 3];
        float* row0 = out + (((size_t)b * 64 + c) * 256 + 2 * hh) * 256;
        float* row1 = row0 + 256;
        for (int j = 0; j < 4; ++j) {
            int w = wvw * 64 + j * 16 + lrow;
            ((float2*)row0)[w] = make_float2(acc[i][j][0] + cb0, acc[i][j][1] + cb1);
            ((float2*)row1)[w] = make_float2(acc[i][j][2] + cb2, acc[i][j][3] + cb3);
        }
    }
}

// ---------------------------------------------------------------------------
extern "C" void kernel_launch(void* const* d_in, const int* in_sizes, int n_in,
                              void* d_out, int out_size, void* d_ws, size_t ws_size,
                              hipStream_t stream) {
    const float* x      = (const float*)d_in[0];
    const float* pixpos = (const float*)d_in[1];
    const float* ppe_w1 = (const float*)d_in[2];
    const float* ppe_b1 = (const float*)d_in[3];
    const float* ppe_w2 = (const float*)d_in[4];
    const float* ppe_b2 = (const float*)d_in[5];
    const float* ln_g   = (const float*)d_in[6];
    const float* ln_b   = (const float*)d_in[7];
    const float* wn_w1  = (const float*)d_in[8];
    const float* wn_b1  = (const float*)d_in[9];
    const float* wn_w2  = (const float*)d_in[10];
    const float* wn_b2  = (const float*)d_in[11];
    const float* bn_w1  = (const float*)d_in[12];
    const float* bn_b1  = (const float*)d_in[13];
    const float* bn_w2  = (const float*)d_in[14];
    const float* bn_b2  = (const float*)d_in[15];
    const float* conv_w = (const float*)d_in[16];
    const float* conv_b = (const float*)d_in[17];
    float* out = (float*)d_out;

    char* wsb = (char*)d_ws;
    float* proc    = (float*)wsb;  wsb += (size_t)NPAT * 1024 * 4;       // 32 MB
    float* summary = (float*)wsb;  wsb += (size_t)NPAT * 64 * 4;         //  2 MB
    __hip_bfloat16* h1 = (__hip_bfloat16*)wsb; wsb += (size_t)NPAT * 256 * 2;  // 4 MB
    float* bias    = (float*)wsb;  wsb += (size_t)NPAT * 64 * 4;         //  2 MB
    __hip_bfloat16* wgt = (__hip_bfloat16*)wsb; wsb += (size_t)NPAT * 4096 * 2; // 64 MB
    __hip_bfloat16* w2t = (__hip_bfloat16*)wsb; wsb += (size_t)2 * 4096 * 256 * 2; // 4 MB
    __hip_bfloat16* cwt_g = (__hip_bfloat16*)wsb;                        // 32 KB

    k_extract<<<1024, 256, 0, stream>>>(x, proc);
    k_summary<<<NPAT, 64, 0, stream>>>(pixpos, ppe_w1, ppe_b1, ppe_w2, ppe_b2, summary);
    k_w2t<<<512, 256, 0, stream>>>(wn_w2, w2t);
    k_cwt<<<64, 256, 0, stream>>>(conv_w, cwt_g);
    for (int i = 0; i < 2; ++i) {
        k_mlp<<<NPAT / 4, 256, 0, stream>>>(summary,
                                            wn_w1 + (size_t)i * 64 * 256, wn_b1 + i * 256,
                                            bn_w1 + (size_t)i * 64 * 256, bn_b1 + i * 256,
                                            bn_w2 + (size_t)i * 256 * 64, bn_b2 + i * 64,
                                            h1, bias);
        k_wgt_mfma<<<2048, 256, 0, stream>>>(h1, w2t + (size_t)i * 4096 * 256,
                                             wn_b2 + (size_t)i * 4096, wgt);
        k_bmm<<<NPAT / 4, 256, 0, stream>>>(proc, wgt, bias, ln_g + i * 64, ln_b + i * 64);
    }
    k_conv_mfma<<<1024, 256, 0, stream>>>(proc, cwt_g, conv_b, out);
}

// Round 5
// 201.592 us; speedup vs baseline: 3.4488x; 1.3121x over previous
//
#include <hip/hip_runtime.h>
#include <hip/hip_bf16.h>

// Problem constants
constexpr int NPAT = 8192;     // B*PH*PW = 8*32*32

typedef __attribute__((ext_vector_type(8))) short short8v;   // 8 bf16
typedef __attribute__((ext_vector_type(4))) float f32x4;

#define GLOAD16(g, l) __builtin_amdgcn_global_load_lds( \
    (const __attribute__((address_space(1))) void*)(g), \
    (__attribute__((address_space(3))) void*)(l), 16, 0, 0)

__device__ inline short bf16s(float f) {
    __hip_bfloat16 h = __float2bfloat16(f);
    return *reinterpret_cast<short*>(&h);
}
__device__ inline unsigned short bf16u(float f) {
    __hip_bfloat16 h = __float2bfloat16(f);
    return *reinterpret_cast<unsigned short*>(&h);
}
__device__ inline float bf2f(short s) {
    return __uint_as_float(((unsigned int)(unsigned short)s) << 16);
}

// ---------------------------------------------------------------------------
// K1: unfold x [8,64,128,128] -> proc bf16 [8192,16,64]
__global__ __launch_bounds__(256) void k_extract(const float* __restrict__ x,
                                                 __hip_bfloat16* __restrict__ proc) {
    __shared__ float tile[64][129];
    int t = threadIdx.x;
    int b = blockIdx.x >> 7, h = blockIdx.x & 127;
    for (int it = 0; it < 8; ++it) {
        int idx = it * 256 + t;
        int c = idx >> 5, w4 = (idx & 31) * 4;
        float4 v = *(const float4*)&x[(((size_t)b * 64 + c) * 128 + h) * 128 + w4];
        tile[c][w4] = v.x; tile[c][w4 + 1] = v.y;
        tile[c][w4 + 2] = v.z; tile[c][w4 + 3] = v.w;
    }
    __syncthreads();
    int ny = (h >> 2) * 32, py = h & 3;
    for (int it = 0; it < 16; ++it) {
        int pw = it * 8 + (t >> 5);          // pixel 0..127
        int cc = (t & 31) * 2;
        int n = (b << 10) + ny + (pw >> 2);
        int p = (py << 2) + (pw & 3);
        unsigned int u = (unsigned int)bf16u(tile[cc][pw]) |
                         ((unsigned int)bf16u(tile[cc + 1][pw]) << 16);
        *(unsigned int*)((__hip_bfloat16*)proc + ((size_t)n << 10) + (p << 6) + cc) = u;
    }
}

// ---------------------------------------------------------------------------
// K2: summary[n, c] = mean_p(pixel_positions) + MLP(coords)  -> bf16
__global__ __launch_bounds__(64) void k_summary(const float* __restrict__ pixpos,
                                                const float* __restrict__ w1,
                                                const float* __restrict__ b1,
                                                const float* __restrict__ w2,
                                                const float* __restrict__ b2,
                                                __hip_bfloat16* __restrict__ summary) {
    __shared__ float h[256];
    int n = blockIdx.x, t = threadIdx.x;  // 64 threads
    int rem = n & 1023;
    float cy = (float)(rem >> 5) * (1.f / 31.f);
    float cx = (float)(rem & 31) * (1.f / 31.f);
    for (int k = t; k < 256; k += 64) {
        float v = cy * w1[k] + cx * w1[256 + k] + b1[k];
        h[k] = v / (1.f + __expf(-v));   // silu
    }
    __syncthreads();
    float acc = b2[t];
    for (int k = 0; k < 256; ++k) acc += h[k] * w2[k * 64 + t];
    float pm = 0.f;
    for (int p = 0; p < 16; ++p) pm += pixpos[p * 64 + t];
    summary[n * 64 + t] = __float2bfloat16(acc + pm * (1.f / 16.f));
}

// ---------------------------------------------------------------------------
// K-prep: w1t[i][512][64] bf16 (wn_w1|bn_w1 transposed), w2bt[i][64][256] bf16
__global__ __launch_bounds__(256) void k_prep(const float* __restrict__ wn_w1,
                                              const float* __restrict__ bn_w1,
                                              const float* __restrict__ bn_w2,
                                              __hip_bfloat16* __restrict__ w1t,
                                              __hip_bfloat16* __restrict__ w2bt) {
    int idx = blockIdx.x * 256 + threadIdx.x;
    if (idx < 2 * 512 * 64) {
        int b = idx >> 15; int r = idx & 32767; int n = r >> 6; int k = r & 63;
        const float* src = (n < 256) ? wn_w1 : bn_w1;
        float v = src[((size_t)b * 64 + k) * 256 + (n & 255)];
        w1t[idx] = __float2bfloat16(v);
    } else {
        int j = idx - 2 * 512 * 64;   // 0..32767
        int b = j >> 14; int r = j & 16383; int c = r >> 8; int k = r & 255;
        float v = bn_w2[((size_t)b * 256 + k) * 64 + c];
        w2bt[j] = __float2bfloat16(v);
    }
}

// ---------------------------------------------------------------------------
// K3 (MFMA): both hyper-blocks at once. Per block: 32 patches.
// Stage1: hcat[m, 0:512] = silu(summary @ [wn_w1|bn_w1] + b). n<256 -> h1 global,
//         n>=256 -> hb LDS (swizzled). Stage2: bias[m,64] = hb @ bn_w2 + b2.
__global__ __launch_bounds__(256) void k_mlp_mfma(const __hip_bfloat16* __restrict__ summary,
                                                  const __hip_bfloat16* __restrict__ w1t_all,
                                                  const float* __restrict__ wn_b1,
                                                  const float* __restrict__ bn_b1,
                                                  const __hip_bfloat16* __restrict__ w2bt_all,
                                                  const float* __restrict__ bn_b2,
                                                  __hip_bfloat16* __restrict__ h1_all,
                                                  float* __restrict__ bias_all) {
    __shared__ short st[32 * 64];    // summary tile, 16B-chunk XOR-swizzled by (m&7)
    __shared__ short hb[32 * 256];   // silu'd bn hidden, 16B-chunk XOR-swizzled by (m&7)
    int t = threadIdx.x;
    int l = t & 63, w = t >> 6;
    int bi = blockIdx.x;
    int i = bi >> 8;                 // hyper-block 0/1
    int m0 = (bi & 255) * 32;
    int lrow = l & 15, hi = l >> 4;

    const __hip_bfloat16* w1t = w1t_all + (size_t)i * 512 * 64;
    const __hip_bfloat16* w2bt = w2bt_all + (size_t)i * 64 * 256;
    const float* b1w = wn_b1 + i * 256;
    const float* b1b = bn_b1 + i * 256;
    const float* b2b = bn_b2 + i * 64;
    __hip_bfloat16* h1out = h1_all + (size_t)i * NPAT * 256;
    float* biasout = bias_all + (size_t)i * NPAT * 64;

    // stage summary tile: 256 chunks of 16B, pre-swizzled global source
    {
        int chunk = w * 64 + l;
        int m = chunk >> 3, q = chunk & 7;
        int gq = q ^ (m & 7);
        GLOAD16((const char*)(summary + ((size_t)(m0 + m) << 6) + (gq << 3)),
                (char*)st + (size_t)(w * 64) * 16);
    }
    __syncthreads();

    // ---- stage 1: n-range per wave = [w*128, w*128+128)
    f32x4 acc[8][2] = {};
    for (int ks = 0; ks < 2; ++ks) {
        short8v a[8], bb[2];
        for (int ii = 0; ii < 8; ++ii) {
            int n = w * 128 + ii * 16 + lrow;
            a[ii] = *(const short8v*)&w1t[(size_t)n * 64 + ks * 32 + hi * 8];
        }
        for (int j = 0; j < 2; ++j) {
            int m = j * 16 + lrow;
            int kk = ks * 4 + hi;
            bb[j] = *(const short8v*)((const char*)st + m * 128 + ((kk ^ (m & 7)) << 4));
        }
        for (int ii = 0; ii < 8; ++ii)
            for (int j = 0; j < 2; ++j)
                acc[ii][j] = __builtin_amdgcn_mfma_f32_16x16x32_bf16(a[ii], bb[j], acc[ii][j], 0, 0, 0);
    }
    // epilogue: n = w*128 + ii*16 + hi*4 + r ; m = m0 + j*16 + lrow
    if (w < 2) {
        for (int ii = 0; ii < 8; ++ii) {
            int n0_ = w * 128 + ii * 16 + hi * 4;
            float4 bw = *(const float4*)&b1w[n0_];
            float bwa[4] = {bw.x, bw.y, bw.z, bw.w};
            for (int j = 0; j < 2; ++j) {
                union { unsigned short s[4]; unsigned long long u; } pk;
                for (int r = 0; r < 4; ++r) {
                    float z = acc[ii][j][r] + bwa[r];
                    pk.s[r] = bf16u(z / (1.f + __expf(-z)));
                }
                int m = m0 + j * 16 + lrow;
                *(unsigned long long*)&h1out[(size_t)m * 256 + n0_] = pk.u;
            }
        }
    } else {
        for (int ii = 0; ii < 8; ++ii) {
            int nb0 = (w - 2) * 128 + ii * 16 + hi * 4;
            float4 bw = *(const float4*)&b1b[nb0];
            float bwa[4] = {bw.x, bw.y, bw.z, bw.w};
            for (int j = 0; j < 2; ++j) {
                union { unsigned short s[4]; unsigned long long u; } pk;
                for (int r = 0; r < 4; ++r) {
                    float z = acc[ii][j][r] + bwa[r];
                    pk.s[r] = bf16u(z / (1.f + __expf(-z)));
                }
                int mloc = j * 16 + lrow;
                int qq = nb0 >> 3;
                *(unsigned long long*)((char*)hb + mloc * 512 +
                                       ((qq ^ (mloc & 7)) << 4) + ((nb0 & 7) << 1)) = pk.u;
            }
        }
    }
    __syncthreads();

    // ---- stage 2: bias[m, c], wave w handles c-range [w*16, w*16+16)
    f32x4 acc2[2] = {};
    for (int ks = 0; ks < 8; ++ks) {
        short8v a2 = *(const short8v*)&w2bt[(size_t)(w * 16 + lrow) * 256 + ks * 32 + hi * 8];
        for (int j = 0; j < 2; ++j) {
            int ml = j * 16 + lrow;
            int kk = ks * 4 + hi;
            short8v b2f = *(const short8v*)((const char*)hb + ml * 512 + ((kk ^ (ml & 7)) << 4));
            acc2[j] = __builtin_amdgcn_mfma_f32_16x16x32_bf16(a2, b2f, acc2[j], 0, 0, 0);
        }
    }
    {
        int c0 = w * 16 + hi * 4;
        float4 bv = *(const float4*)&b2b[c0];
        for (int j = 0; j < 2; ++j) {
            int m = m0 + j * 16 + lrow;
            float4 o;
            o.x = acc2[j][0] + bv.x; o.y = acc2[j][1] + bv.y;
            o.z = acc2[j][2] + bv.z; o.w = acc2[j][3] + bv.w;
            *(float4*)&biasout[(size_t)m * 64 + c0] = o;
        }
    }
}

// ---------------------------------------------------------------------------
// K-cvt: transpose+convert wn_w2 [2][256][4096] f32 -> w2t [2][4096][256] bf16
__global__ __launch_bounds__(256) void k_w2t(const float* __restrict__ w2,
                                             __hip_bfloat16* __restrict__ w2t) {
    __shared__ float tile[64][65];
    int bid = blockIdx.x;          // 0..511
    int b = bid >> 8;
    int rem = bid & 255;
    int kt = rem >> 6;
    int nt = rem & 63;
    int t = threadIdx.x;
    const float* src = w2 + (size_t)b * 256 * 4096 + (size_t)(kt * 64) * 4096 + nt * 64;
    for (int it = 0; it < 16; ++it) {
        int idx = t + it * 256;
        int r = idx >> 6, c = idx & 63;
        tile[r][c] = src[(size_t)r * 4096 + c];
    }
    __syncthreads();
    __hip_bfloat16* dst = w2t + (size_t)b * 4096 * 256 + (size_t)(nt * 64) * 256 + kt * 64;
    for (int it = 0; it < 16; ++it) {
        int idx = t + it * 256;
        int rr = idx >> 6, cc = idx & 63;
        dst[rr * 256 + cc] = __float2bfloat16(tile[cc][rr]);
    }
}

// ---------------------------------------------------------------------------
// K-cvt2: conv_w [64][256] f32 -> cwt_g [256 oc][64 cc] bf16, XOR-pre-swizzled
__global__ __launch_bounds__(256) void k_cwt(const float* __restrict__ cw,
                                             __hip_bfloat16* __restrict__ cwt_g) {
    int idx = blockIdx.x * 256 + threadIdx.x;   // 0..16383
    int oc = idx >> 6, cc = idx & 63;
    float v = cw[cc * 256 + oc];
    int el = oc * 64 + (((cc >> 3) ^ (oc & 7)) << 3) + (cc & 7);
    cwt_g[el] = __float2bfloat16(v);
}

// ---------------------------------------------------------------------------
// K4: MFMA GEMM. wgt[m,n] = h1[m,:256] @ w2t[n,:256] + b2[n], bf16 out.
__global__ __launch_bounds__(256) void k_wgt_mfma(const __hip_bfloat16* __restrict__ h1,
                                                  const __hip_bfloat16* __restrict__ w2t,
                                                  const float* __restrict__ b2,
                                                  __hip_bfloat16* __restrict__ wgt) {
    __shared__ short As[128 * 32];
    __shared__ short Bs[128 * 32];
    int t = threadIdx.x;
    int l = t & 63, w = t >> 6;
    int mt = blockIdx.x & 63, nt = blockIdx.x >> 6;
    int m0 = mt << 7, n0 = nt << 7;
    int wr = w >> 1, wc = w & 1;
    int lrow = l & 15;
    int lk8 = (l >> 4) << 3;

    f32x4 acc[4][4] = {};

    const char* gA = (const char*)(h1 + (size_t)m0 * 256);
    const char* gB = (const char*)(w2t + (size_t)n0 * 256);
    char* lA = (char*)As + (w << 10);
    char* lB = (char*)Bs + (w << 10);

    for (int k0 = 0; k0 < 256; k0 += 32) {
        {
            int cid0 = t;
            int row0 = cid0 >> 2, ib0 = (cid0 & 3) << 3;
            GLOAD16(gA + ((size_t)row0 * 256 + k0 + ib0) * 2, lA);
            GLOAD16(gB + ((size_t)row0 * 256 + k0 + ib0) * 2, lB);
            int cid1 = 256 + t;
            int row1 = cid1 >> 2, ib1 = (cid1 & 3) << 3;
            GLOAD16(gA + ((size_t)row1 * 256 + k0 + ib1) * 2, lA + 4096);
            GLOAD16(gB + ((size_t)row1 * 256 + k0 + ib1) * 2, lB + 4096);
        }
        __syncthreads();
        short8v a[4], b[4];
        for (int i = 0; i < 4; ++i)
            a[i] = *(const short8v*)&Bs[(wc * 64 + i * 16 + lrow) * 32 + lk8];
        for (int j = 0; j < 4; ++j)
            b[j] = *(const short8v*)&As[(wr * 64 + j * 16 + lrow) * 32 + lk8];
        for (int i = 0; i < 4; ++i)
            for (int j = 0; j < 4; ++j)
                acc[i][j] = __builtin_amdgcn_mfma_f32_16x16x32_bf16(a[i], b[j], acc[i][j], 0, 0, 0);
        __syncthreads();
    }

    for (int i = 0; i < 4; ++i) {
        int nb = n0 + wc * 64 + i * 16 + ((l >> 4) << 2);
        float4 bv = *(const float4*)&b2[nb];
        float bva[4] = {bv.x, bv.y, bv.z, bv.w};
        for (int j = 0; j < 4; ++j) {
            int m = m0 + wr * 64 + j * 16 + (l & 15);
            union { __hip_bfloat16 h[4]; uint2 u; } st;
            for (int r = 0; r < 4; ++r)
                st.h[r] = __float2bfloat16(acc[i][j][r] + bva[r]);
            *(uint2*)&wgt[(size_t)m * 4096 + nb] = st.u;
        }
    }
}

// ---------------------------------------------------------------------------
// K5 (MFMA): per patch (one wave): nm = LN(proc); proc += wgt @ nm^T + bias.
__global__ __launch_bounds__(256) void k_bmm(__hip_bfloat16* __restrict__ proc,
                                             const __hip_bfloat16* __restrict__ wgt,
                                             const float* __restrict__ bias,
                                             const float* __restrict__ ln_g,
                                             const float* __restrict__ ln_b) {
    __shared__ short nm_lds[4][16][72];
    int t = threadIdx.x;
    int w = t >> 6, l = t & 63;
    int n = blockIdx.x * 4 + w;
    int p = l & 15, hi = l >> 4;

    // ---- load 16 channels (hi*16..) of token p
    const __hip_bfloat16* prow = proc + ((size_t)n << 10) + (p << 6) + (hi << 4);
    short8v r0 = *(const short8v*)prow;
    short8v r1 = *(const short8v*)(prow + 8);
    float pr[16];
    for (int i = 0; i < 8; ++i) { pr[i] = bf2f(r0[i]); pr[8 + i] = bf2f(r1[i]); }

    // ---- LN stats across the 4 lanes holding token p
    float s = 0.f, s2 = 0.f;
    for (int i = 0; i < 16; ++i) { s += pr[i]; s2 += pr[i] * pr[i]; }
    s += __shfl_xor(s, 16);  s2 += __shfl_xor(s2, 16);
    s += __shfl_xor(s, 32);  s2 += __shfl_xor(s2, 32);
    float mean = s * (1.f / 64.f);
    float var = s2 * (1.f / 64.f) - mean * mean;
    float rinv = rsqrtf(var + 1e-5f);

    // ---- normalize, bf16, stage to LDS
    float gg[16], bb_[16];
    {
        const float* gp = ln_g + (hi << 4);
        const float* bp = ln_b + (hi << 4);
        *(float4*)(gg)      = *(const float4*)(gp);
        *(float4*)(gg + 4)  = *(const float4*)(gp + 4);
        *(float4*)(gg + 8)  = *(const float4*)(gp + 8);
        *(float4*)(gg + 12) = *(const float4*)(gp + 12);
        *(float4*)(bb_)      = *(const float4*)(bp);
        *(float4*)(bb_ + 4)  = *(const float4*)(bp + 4);
        *(float4*)(bb_ + 8)  = *(const float4*)(bp + 8);
        *(float4*)(bb_ + 12) = *(const float4*)(bp + 12);
    }
    short8v nm0, nm1;
    for (int i = 0; i < 8; ++i)
        nm0[i] = bf16s((pr[i] - mean) * rinv * gg[i] + bb_[i]);
    for (int i = 0; i < 8; ++i)
        nm1[i] = bf16s((pr[8 + i] - mean) * rinv * gg[8 + i] + bb_[8 + i]);
    *(short8v*)&nm_lds[w][p][hi * 16]     = nm0;
    *(short8v*)&nm_lds[w][p][hi * 16 + 8] = nm1;
    __syncthreads();

    // ---- A-fragments straight from global wgt row
    const __hip_bfloat16* wrow = wgt + ((size_t)n << 12);
    short8v af[4][2];
    for (int ib = 0; ib < 4; ++ib)
        for (int ks = 0; ks < 2; ++ks)
            af[ib][ks] = *(const short8v*)&wrow[(ib * 16 + p) * 64 + ks * 32 + hi * 8];

    short8v bf0 = *(const short8v*)&nm_lds[w][p][hi * 8];
    short8v bf1 = *(const short8v*)&nm_lds[w][p][32 + hi * 8];

    f32x4 acc[4] = {};
    for (int ib = 0; ib < 4; ++ib) {
        acc[ib] = __builtin_amdgcn_mfma_f32_16x16x32_bf16(af[ib][0], bf0, acc[ib], 0, 0, 0);
        acc[ib] = __builtin_amdgcn_mfma_f32_16x16x32_bf16(af[ib][1], bf1, acc[ib], 0, 0, 0);
    }

    // ---- epilogue: proc[p][i] += D[i][p] + bias[i]   (bf16 in/out)
    __hip_bfloat16* orow = proc + ((size_t)n << 10) + (p << 6);
    const float* brow = bias + ((size_t)n << 6);
    for (int ib = 0; ib < 4; ++ib) {
        int i0 = ib * 16 + hi * 4;
        unsigned long long rr = *(const unsigned long long*)&orow[i0];
        float4 bsv = *(const float4*)&brow[i0];
        float ba[4] = {bsv.x, bsv.y, bsv.z, bsv.w};
        union { unsigned short s[4]; unsigned long long u; } stp;
        for (int r = 0; r < 4; ++r) {
            float res = bf2f((short)((rr >> (16 * r)) & 0xffff));
            stp.s[r] = bf16u(acc[ib][r] + ba[r] + res);
        }
        *(unsigned long long*)&orow[i0] = stp.u;
    }
}

// ---------------------------------------------------------------------------
// K6: 1x1 conv (64->256) + pixel shuffle, MFMA; proc is bf16 now.
__global__ __launch_bounds__(256) void k_conv_mfma(const __hip_bfloat16* __restrict__ proc,
                                                   const __hip_bfloat16* __restrict__ cwt_g,
                                                   const float* __restrict__ cb,
                                                   float* __restrict__ out) {
    __shared__ short cwt[256 * 64];
    __shared__ short msb[128 * 64];
    __shared__ float cbl[256];
    int t = threadIdx.x;
    int l = t & 63, wv = t >> 6;
    int b = blockIdx.x >> 7, hh = blockIdx.x & 127;

    for (int it = 0; it < 8; ++it) {
        int cid0 = it * 256 + wv * 64;
        GLOAD16((const char*)cwt_g + ((size_t)(cid0 + l) << 4),
                (char*)cwt + ((size_t)cid0 << 4));
    }
    cbl[t] = cb[t];
    // stage merged tile straight from bf16 proc, pre-swizzled global source
    int ny = (hh >> 2) * 32, py = hh & 3;
    for (int it = 0; it < 4; ++it) {
        int chunk = it * 256 + wv * 64 + l;
        int w = chunk >> 3, q = chunk & 7;
        int n = (b << 10) + ny + (w >> 2);
        int p = (py << 2) + (w & 3);
        int gq = q ^ (w & 7);
        GLOAD16((const char*)proc + (((size_t)n << 10) + (p << 6) + (gq << 3)) * 2,
                (char*)msb + (size_t)(it * 256 + wv * 64) * 16);
    }
    __syncthreads();

    int wvo = wv >> 1, wvw = wv & 1;
    int lrow = l & 15, lhi = l >> 4;
    f32x4 acc[8][4] = {};
    for (int ks = 0; ks < 2; ++ks) {
        int q = ks * 4 + lhi;
        short8v a[8], bb[4];
        for (int i = 0; i < 8; ++i) {
            int ocr = wvo * 128 + i * 16 + lrow;
            a[i] = *(const short8v*)((const char*)cwt + ocr * 128 + ((q ^ (ocr & 7)) << 4));
        }
        for (int j = 0; j < 4; ++j) {
            int wr = wvw * 64 + j * 16 + lrow;
            bb[j] = *(const short8v*)((const char*)msb + wr * 128 + ((q ^ (wr & 7)) << 4));
        }
        for (int i = 0; i < 8; ++i)
            for (int j = 0; j < 4; ++j)
                acc[i][j] = __builtin_amdgcn_mfma_f32_16x16x32_bf16(a[i], bb[j], acc[i][j], 0, 0, 0);
    }

    for (int i = 0; i < 8; ++i) {
        int oc4 = wvo * 128 + i * 16 + lhi * 4;
        int c = oc4 >> 2;
        float cb0 = cbl[oc4], cb1 = cbl[oc4 + 1], cb2 = cbl[oc4 + 2], cb3 = cbl[oc4 + 3];
        float* row0 = out + (((size_t)b * 64 + c) * 256 + 2 * hh) * 256;
        float* row1 = row0 + 256;
        for (int j = 0; j < 4; ++j) {
            int w = wvw * 64 + j * 16 + lrow;
            ((float2*)row0)[w] = make_float2(acc[i][j][0] + cb0, acc[i][j][1] + cb1);
            ((float2*)row1)[w] = make_float2(acc[i][j][2] + cb2, acc[i][j][3] + cb3);
        }
    }
}

// ---------------------------------------------------------------------------
extern "C" void kernel_launch(void* const* d_in, const int* in_sizes, int n_in,
                              void* d_out, int out_size, void* d_ws, size_t ws_size,
                              hipStream_t stream) {
    const float* x      = (const float*)d_in[0];
    const float* pixpos = (const float*)d_in[1];
    const float* ppe_w1 = (const float*)d_in[2];
    const float* ppe_b1 = (const float*)d_in[3];
    const float* ppe_w2 = (const float*)d_in[4];
    const float* ppe_b2 = (const float*)d_in[5];
    const float* ln_g   = (const float*)d_in[6];
    const float* ln_b   = (const float*)d_in[7];
    const float* wn_w1  = (const float*)d_in[8];
    const float* wn_b1  = (const float*)d_in[9];
    const float* wn_w2  = (const float*)d_in[10];
    const float* wn_b2  = (const float*)d_in[11];
    const float* bn_w1  = (const float*)d_in[12];
    const float* bn_b1  = (const float*)d_in[13];
    const float* bn_w2  = (const float*)d_in[14];
    const float* bn_b2  = (const float*)d_in[15];
    const float* conv_w = (const float*)d_in[16];
    const float* conv_b = (const float*)d_in[17];
    float* out = (float*)d_out;

    char* wsb = (char*)d_ws;
    __hip_bfloat16* procb = (__hip_bfloat16*)wsb; wsb += (size_t)NPAT * 1024 * 2;     // 16 MB
    __hip_bfloat16* wgt   = (__hip_bfloat16*)wsb; wsb += (size_t)NPAT * 4096 * 2;     // 64 MB
    __hip_bfloat16* h1    = (__hip_bfloat16*)wsb; wsb += (size_t)2 * NPAT * 256 * 2;  //  8 MB
    __hip_bfloat16* w2t   = (__hip_bfloat16*)wsb; wsb += (size_t)2 * 4096 * 256 * 2;  //  4 MB
    float* bias           = (float*)wsb;          wsb += (size_t)2 * NPAT * 64 * 4;   //  4 MB
    __hip_bfloat16* summ  = (__hip_bfloat16*)wsb; wsb += (size_t)NPAT * 64 * 2;       //  1 MB
    __hip_bfloat16* w1t   = (__hip_bfloat16*)wsb; wsb += (size_t)2 * 512 * 64 * 2;    // 128 KB
    __hip_bfloat16* w2bt  = (__hip_bfloat16*)wsb; wsb += (size_t)2 * 64 * 256 * 2;    //  64 KB
    __hip_bfloat16* cwt_g = (__hip_bfloat16*)wsb;                                     //  32 KB

    k_extract<<<1024, 256, 0, stream>>>(x, procb);
    k_summary<<<NPAT, 64, 0, stream>>>(pixpos, ppe_w1, ppe_b1, ppe_w2, ppe_b2, summ);
    k_w2t<<<512, 256, 0, stream>>>(wn_w2, w2t);
    k_cwt<<<64, 256, 0, stream>>>(conv_w, cwt_g);
    k_prep<<<384, 256, 0, stream>>>(wn_w1, bn_w1, bn_w2, w1t, w2bt);
    k_mlp_mfma<<<512, 256, 0, stream>>>(summ, w1t, wn_b1, bn_b1, w2bt, bn_b2, h1, bias);
    for (int i = 0; i < 2; ++i) {
        k_wgt_mfma<<<2048, 256, 0, stream>>>(h1 + (size_t)i * NPAT * 256,
                                             w2t + (size_t)i * 4096 * 256,
                                             wn_b2 + (size_t)i * 4096, wgt);
        k_bmm<<<NPAT / 4, 256, 0, stream>>>(procb, wgt, bias + (size_t)i * NPAT * 64,
                                            ln_g + i * 64, ln_b + i * 64);
    }
    k_conv_mfma<<<1024, 256, 0, stream>>>(procb, cwt_g, conv_b, out);
}